// Round 4
// baseline (699.053 us; speedup 1.0000x reference)
//
#include <hip/hip_runtime.h>
#include <stdint.h>

#define K_TOP 10000
#define CAP   16384            // 2^14, candidate slack per level
#define N0    98304
#define N1    24576
#define N2    6144
#define N3    1536
#define N4    384
#define NSMALL (N2 + N3 + N4)  // 8064
#define NROWS  (2 * K_TOP + NSMALL)   // 28064
#define HALF   (NROWS / 2)            // 14032
#define MAXGT 2048
#define NBLK  256              // == CU count: 1 block/CU, co-residency guaranteed
#define NTHR  512
#define JSPLIT 8

struct State {
    unsigned hist[2][256];
    unsigned prefix[2];
    unsigned remK[2];
    unsigned candCount[2];
    unsigned barCnt;
    unsigned barGen;
};

struct Ptrs { const float* anc[5]; const float* cls[5]; const float* reg[5]; };

// order-preserving float->uint map (ascending uint == ascending float)
__device__ __forceinline__ unsigned f2ord(float f) {
    unsigned u = __float_as_uint(f);
    return (u & 0x80000000u) ? ~u : (u | 0x80000000u);
}

__global__ void k_init(State* st) {
    unsigned t = threadIdx.x;
    unsigned* w = (unsigned*)st;
    for (unsigned i = t; i < sizeof(State) / 4; i += blockDim.x) w[i] = 0;
    __syncthreads();
    if (t < 2) st->remK[t] = K_TOP;
}

// grid barrier: device-scope release/acquire; cnt reset by last arriver.
__device__ __forceinline__ void gbar(unsigned* cnt, unsigned* gen) {
    __syncthreads();
    if (threadIdx.x == 0) {
        unsigned g = __hip_atomic_load(gen, __ATOMIC_RELAXED, __HIP_MEMORY_SCOPE_AGENT);
        if (__hip_atomic_fetch_add(cnt, 1u, __ATOMIC_ACQ_REL, __HIP_MEMORY_SCOPE_AGENT) == NBLK - 1u) {
            __hip_atomic_store(cnt, 0u, __ATOMIC_RELAXED, __HIP_MEMORY_SCOPE_AGENT);
            __hip_atomic_fetch_add(gen, 1u, __ATOMIC_ACQ_REL, __HIP_MEMORY_SCOPE_AGENT);
        } else {
            while (__hip_atomic_load(gen, __ATOMIC_ACQUIRE, __HIP_MEMORY_SCOPE_AGENT) == g)
                __builtin_amdgcn_s_sleep(2);
        }
    }
    __syncthreads();
}

__device__ __forceinline__ int row2lev(int r) {
    if (r < K_TOP) return 0;
    if (r < 2 * K_TOP) return 1;
    if (r < 2 * K_TOP + N2) return 2;
    if (r < 2 * K_TOP + N2 + N3) return 3;
    return 4;
}

__device__ __forceinline__ void decode_row(const Ptrs& p, int lev, int ai, int r,
                                           float* __restrict__ out,
                                           float4* __restrict__ boxws,
                                           unsigned* __restrict__ rowAi) {
    float4 a4 = ((const float4*)p.anc[lev])[ai];
    float sc = p.cls[lev][ai];
    float4 r4 = *(const float4*)(p.reg[lev] + (size_t)ai * 8);
    float w = a4.z - a4.x + 1.0f, h = a4.w - a4.y + 1.0f;
    float cx = a4.x + 0.5f * w,  cy = a4.y + 0.5f * h;
    float pcx = r4.x * w + cx,   pcy = r4.y * h + cy;
    float pw = expf(r4.z) * w,   ph = expf(r4.w) * h;
    float bx1 = pcx - 0.5f * pw, by1 = pcy - 0.5f * ph;
    float bx2 = pcx + 0.5f * pw - 1.0f, by2 = pcy + 0.5f * ph - 1.0f;
    float* o = out + (size_t)r * 10;
    o[0] = bx1; o[1] = by1; o[2] = bx2; o[3] = by2;
    o[4] = 1.0f / (1.0f + expf(-sc)); o[5] = 1.0f;
    boxws[r] = make_float4(bx1, by1, bx2, by2);
    rowAi[r] = (unsigned)ai;
}

__global__ void __launch_bounds__(NTHR)
k_fused(Ptrs p, const float* __restrict__ gt, const int* __restrict__ numgt,
        State* st, unsigned long long* __restrict__ cand,
        unsigned short* __restrict__ part, unsigned* __restrict__ rowAi,
        float4* __restrict__ boxws, float* __restrict__ out) {
    __shared__ float4 sg[MAXGT];       // 32 KiB (GT boxes; aliased as rank tile)
    __shared__ float  sarea[MAXGT];    // 8 KiB
    __shared__ unsigned lh[512];       // 2 KiB (2 levels x 256 bins)

    unsigned tid  = threadIdx.x;
    unsigned gtid = blockIdx.x * NTHR + tid;
    unsigned* bc = &st->barCnt;
    unsigned* bg = &st->barGen;
    const float* cls0 = p.cls[0];
    const float* cls1 = p.cls[1];

    // ======== radix passes 0,1 (top-16-bit threshold prefix) ========
    for (int pass = 0; pass < 2; pass++) {
        lh[tid] = 0;
        __syncthreads();
        unsigned pre0 = st->prefix[0], pre1 = st->prefix[1];
        unsigned maskAbove = (pass == 0) ? 0u : 0xFF000000u;
        int shift = (pass == 0) ? 24 : 16;
        for (unsigned e = gtid; e < N0 + N1; e += NBLK * NTHR) {
            int lev = (e < N0) ? 0 : 1;
            float v = lev ? cls1[e - N0] : cls0[e];
            unsigned key = f2ord(v);
            unsigned pre = lev ? pre1 : pre0;
            if ((key & maskAbove) == (pre & maskAbove))
                atomicAdd(&lh[lev * 256 + ((key >> shift) & 0xFFu)], 1u);
        }
        __syncthreads();
        if (lh[tid]) atomicAdd(&st->hist[0][0] + tid, lh[tid]);
        gbar(bc, bg);

        if (blockIdx.x == 0) {           // pick: block 0, both levels
            unsigned lev = tid >> 8, bin = tid & 255u;
            lh[tid] = st->hist[lev][bin];
            st->hist[lev][bin] = 0;      // reset for next pass
            __syncthreads();
            unsigned cum = 0;            // count with digit > bin
            for (unsigned e = bin + 1; e < 256; e++) cum += lh[lev * 256 + e];
            unsigned remK = st->remK[lev];
            if (cum < remK && cum + lh[tid] >= remK) {
                st->remK[lev] = remK - cum;
                st->prefix[lev] |= bin << shift;
            }
        }
        gbar(bc, bg);
    }

    // ======== compact: keys >= 16-bit threshold ========
    {
        unsigned T0 = st->prefix[0], T1 = st->prefix[1];
        for (unsigned e = gtid; e < N0 + N1; e += NBLK * NTHR) {
            int lev = (e < N0) ? 0 : 1;
            unsigned idx = lev ? (e - N0) : e;
            float v = lev ? cls1[idx] : cls0[idx];
            unsigned key = f2ord(v);
            unsigned T = lev ? T1 : T0;
            if (key >= T) {
                unsigned slot = atomicAdd(&st->candCount[lev], 1u);
                if (slot < CAP)
                    cand[(size_t)lev * CAP + slot] =
                        ((unsigned long long)key << 32) | (unsigned)(~idx);
            }
        }
    }
    gbar(bc, bg);

    unsigned cnt0 = st->candCount[0]; if (cnt0 > CAP) cnt0 = CAP;
    unsigned cnt1 = st->candCount[1]; if (cnt1 > CAP) cnt1 = CAP;

    // ======== partial counting-rank: 128 blocks (lev x 8 ichunk x 8 jchunk) ========
    if (blockIdx.x < 128) {
        int lev = blockIdx.x & 1;
        unsigned cnt = lev ? cnt1 : cnt0;
        unsigned ic = (blockIdx.x >> 1) & 7;
        unsigned jc = blockIdx.x >> 4;
        unsigned ibase = ic * 2048;
        if (ibase < cnt) {
            unsigned long long ci[4];
            #pragma unroll
            for (int c = 0; c < 4; c++) {
                unsigned i = ibase + tid + c * NTHR;
                ci[c] = (i < cnt) ? cand[(size_t)lev * CAP + i] : 0xFFFFFFFFFFFFFFFFull;
            }
            unsigned jchunk = (cnt + JSPLIT - 1) / JSPLIT;
            unsigned j0 = jc * jchunk;
            unsigned j1 = j0 + jchunk; if (j1 > cnt) j1 = cnt;
            unsigned rk0 = 0, rk1 = 0, rk2 = 0, rk3 = 0;
            unsigned long long* tile = (unsigned long long*)sg;
            for (unsigned base = j0; base < j1; base += NTHR) {
                unsigned j = base + tid;
                tile[tid] = (j < j1) ? cand[(size_t)lev * CAP + j] : 0ull;
                __syncthreads();
                unsigned lim = j1 - base; if (lim > NTHR) lim = NTHR;
                #pragma unroll 4
                for (unsigned t = 0; t < lim; t++) {
                    unsigned long long cj = tile[t];
                    rk0 += (cj > ci[0]) ? 1u : 0u;
                    rk1 += (cj > ci[1]) ? 1u : 0u;
                    rk2 += (cj > ci[2]) ? 1u : 0u;
                    rk3 += (cj > ci[3]) ? 1u : 0u;
                }
                __syncthreads();
            }
            unsigned short* pp = part + ((size_t)(lev * JSPLIT + jc)) * CAP;
            pp[ibase + tid]            = (unsigned short)rk0;
            pp[ibase + tid + NTHR]     = (unsigned short)rk1;
            pp[ibase + tid + 2 * NTHR] = (unsigned short)rk2;
            pp[ibase + tid + 3 * NTHR] = (unsigned short)rk3;
        }
    }
    gbar(bc, bg);

    // ======== decode + scatter (one item per thread, no loop) ========
    {
        unsigned item = gtid;
        if (item < 2 * CAP) {
            int lev = item >> 14;
            unsigned i = item & (CAP - 1);
            unsigned cnt = lev ? cnt1 : cnt0;
            if (i < cnt) {
                unsigned rank = 0;
                #pragma unroll
                for (int s = 0; s < JSPLIT; s++)
                    rank += part[((size_t)(lev * JSPLIT + s)) * CAP + i];
                if (rank < K_TOP) {
                    int ai = (int)~(unsigned)cand[(size_t)lev * CAP + i];
                    decode_row(p, lev, ai, lev * K_TOP + rank, out, boxws, rowAi);
                }
            }
        } else if (item < 2 * CAP + NSMALL) {
            int rr = (int)item - 2 * CAP;           // 0..8063
            int lev, ai;
            if (rr < N2)            { lev = 2; ai = rr; }
            else if (rr < N2 + N3)  { lev = 3; ai = rr - N2; }
            else                    { lev = 4; ai = rr - N2 - N3; }
            decode_row(p, lev, ai, 2 * K_TOP + rr, out, boxws, rowAi);
        }
    }
    gbar(bc, bg);

    // ======== IoU argmax + targets: 2 rows/thread, 8 subs/row ========
    int ng = *numgt; if (ng > MAXGT) ng = MAXGT;
    for (int g = (int)tid; g < ng; g += NTHR) {
        float x1 = gt[g * 5 + 0], y1 = gt[g * 5 + 1];
        float x2 = gt[g * 5 + 2], y2 = gt[g * 5 + 3];
        sg[g] = make_float4(x1, y1, x2, y2);
        sarea[g] = (x2 - x1 + 1.0f) * (y2 - y1 + 1.0f);
    }
    __syncthreads();

    unsigned u = gtid >> 3;
    int sub = (int)(gtid & 7);
    if (u < HALF) {                       // wave-aligned guard (112256 = 1754 waves)
        int r0 = (int)u, r1 = (int)u + HALF;
        float4 bA = boxws[r0];
        float4 bB = boxws[r1];
        float areaA = (bA.z - bA.x + 1.0f) * (bA.w - bA.y + 1.0f);
        float areaB = (bB.z - bB.x + 1.0f) * (bB.w - bB.y + 1.0f);
        int chunk = (ng + 7) >> 3;
        int g0 = sub * chunk;
        int g1 = g0 + chunk; if (g1 > ng) g1 = ng; if (g0 > g1) g0 = g1;
        // iou_a > iou_b  <=>  I_a*S_b > I_b*S_a  with S = areaBox + areaGT
        float IbA = 0.f, SbA = 1.f; int argA = (sub == 0) ? 0 : 0x7FFFFFFF;
        float IbB = 0.f, SbB = 1.f; int argB = (sub == 0) ? 0 : 0x7FFFFFFF;
        #pragma unroll 2
        for (int g = g0; g < g1; ++g) {
            float4 gb = sg[g];
            float sa = sarea[g];
            float iwA = fminf(bA.z, gb.z) - fmaxf(bA.x, gb.x) + 1.0f; iwA = fmaxf(iwA, 0.f);
            float ihA = fminf(bA.w, gb.w) - fmaxf(bA.y, gb.y) + 1.0f; ihA = fmaxf(ihA, 0.f);
            float IA = iwA * ihA, SA = areaA + sa;
            if (IA * SbA > IbA * SA) { IbA = IA; SbA = SA; argA = g; }
            float iwB = fminf(bB.z, gb.z) - fmaxf(bB.x, gb.x) + 1.0f; iwB = fmaxf(iwB, 0.f);
            float ihB = fminf(bB.w, gb.w) - fmaxf(bB.y, gb.y) + 1.0f; ihB = fmaxf(ihB, 0.f);
            float IB = iwB * ihB, SB = areaB + sa;
            if (IB * SbB > IbB * SB) { IbB = IB; SbB = SB; argB = g; }
        }
        #pragma unroll
        for (int off = 1; off < 8; off <<= 1) {   // max iou, tie -> min index
            float oI = __shfl_xor(IbA, off), oS = __shfl_xor(SbA, off);
            int   oa = __shfl_xor(argA, off);
            float x = oI * SbA, y = IbA * oS;
            if (x > y || (x == y && oa < argA)) { IbA = oI; SbA = oS; argA = oa; }
            oI = __shfl_xor(IbB, off); oS = __shfl_xor(SbB, off);
            oa = __shfl_xor(argB, off);
            x = oI * SbB; y = IbB * oS;
            if (x > y || (x == y && oa < argB)) { IbB = oI; SbB = oS; argB = oa; }
        }
        if (sub < 2) {
            int r  = sub ? r1 : r0;
            int ag = sub ? argB : argA;
            int lev = row2lev(r);
            float4 a4 = ((const float4*)p.anc[lev])[rowAi[r]];
            float w = a4.z - a4.x + 1.0f, h = a4.w - a4.y + 1.0f;
            float cx = a4.x + 0.5f * w,  cy = a4.y + 0.5f * h;
            float4 gb = sg[ag];
            float gw = gb.z - gb.x + 1.0f, gh = gb.w - gb.y + 1.0f;
            float gcx = gb.x + 0.5f * gw, gcy = gb.y + 0.5f * gh;
            float* o = out + (size_t)r * 10;
            o[6] = (gcx - cx) / w;
            o[7] = (gcy - cy) / h;
            o[8] = logf(gw / w);
            o[9] = logf(gh / h);
        }
    }
}

extern "C" void kernel_launch(void* const* d_in, const int* in_sizes, int n_in,
                              void* d_out, int out_size, void* d_ws, size_t ws_size,
                              hipStream_t stream) {
    Ptrs p;
    bool interleaved = (in_sizes[2] == N0 * 8);
    for (int l = 0; l < 5; l++) {
        if (interleaved) {
            p.anc[l] = (const float*)d_in[3 * l + 0];
            p.cls[l] = (const float*)d_in[3 * l + 1];
            p.reg[l] = (const float*)d_in[3 * l + 2];
        } else {
            p.anc[l] = (const float*)d_in[l];
            p.cls[l] = (const float*)d_in[5 + l];
            p.reg[l] = (const float*)d_in[10 + l];
        }
    }
    const float* gt    = (const float*)d_in[15];
    const int*   numgt = (const int*)d_in[16];

    char* ws = (char*)d_ws;
    size_t off = 0;
    State* st = (State*)(ws + off);                              off += 4096;
    unsigned long long* cand = (unsigned long long*)(ws + off);  off += (size_t)2 * CAP * 8;          // 256 KiB
    unsigned short* part = (unsigned short*)(ws + off);          off += (size_t)2 * JSPLIT * CAP * 2; // 512 KiB
    unsigned* rowAi = (unsigned*)(ws + off);                     off += (size_t)NROWS * 4;            // 110 KiB
    off = (off + 15) & ~(size_t)15;
    float4* boxws = (float4*)(ws + off);                         off += (size_t)NROWS * 16;           // 439 KiB

    float* out = (float*)d_out;

    k_init<<<dim3(1), dim3(NTHR), 0, stream>>>(st);
    k_fused<<<dim3(NBLK), dim3(NTHR), 0, stream>>>(p, gt, numgt, st, cand, part, rowAi, boxws, out);
}

// Round 5
// 636.766 us; speedup vs baseline: 1.0978x; 1.0978x over previous
//
#include <hip/hip_runtime.h>
#include <stdint.h>

#define K_TOP 10000
#define CAP   16384            // candidate slack per level (cnt ~ 10.3k)
#define N0    98304
#define N1    24576
#define N2    6144
#define N3    1536
#define N4    384
#define NSMALL (N2 + N3 + N4)  // 8064
#define NROWS  (2 * K_TOP + NSMALL)   // 28064
#define HALF   (NROWS / 2)            // 14032
#define MAXGT 2048
#define NBLK  256              // == CU count
#define NTHR  512
#define JSPLIT 8
#define ICHUNK 1024            // 16 i-chunks per level

struct State {
    unsigned prefix[2];        // threshold key (top16<<16)
    unsigned candCount[2];
    unsigned barCnt;
    unsigned barGen;
};

struct Ptrs { const float* anc[5]; const float* cls[5]; const float* reg[5]; };

__device__ __forceinline__ unsigned f2ord(float f) {
    unsigned u = __float_as_uint(f);
    return (u & 0x80000000u) ? ~u : (u | 0x80000000u);
}

__global__ void k_init(State* st, unsigned* hist16) {
    unsigned g = blockIdx.x * blockDim.x + threadIdx.x;
    if (g < 2u * 65536u) hist16[g] = 0;
    if (g < sizeof(State) / 4) ((unsigned*)st)[g] = 0;
}

// Grid barrier. CRITICAL on gfx950: poll RELAXED (no per-poll cache invalidate);
// exactly one release fence (wbl2) before arrival and one acquire fence
// (buffer_inv) after the barrier opens.
__device__ __forceinline__ void gbar(unsigned* cnt, unsigned* gen) {
    __syncthreads();
    if (threadIdx.x == 0) {
        unsigned g = __hip_atomic_load(gen, __ATOMIC_RELAXED, __HIP_MEMORY_SCOPE_AGENT);
        __builtin_amdgcn_fence(__ATOMIC_RELEASE, "agent");     // publish block's stores
        unsigned a = __hip_atomic_fetch_add(cnt, 1u, __ATOMIC_RELAXED, __HIP_MEMORY_SCOPE_AGENT);
        if (a == NBLK - 1u) {
            __hip_atomic_store(cnt, 0u, __ATOMIC_RELAXED, __HIP_MEMORY_SCOPE_AGENT);
            __hip_atomic_fetch_add(gen, 1u, __ATOMIC_RELAXED, __HIP_MEMORY_SCOPE_AGENT);
        } else {
            while (__hip_atomic_load(gen, __ATOMIC_RELAXED, __HIP_MEMORY_SCOPE_AGENT) == g)
                __builtin_amdgcn_s_sleep(8);
        }
        __builtin_amdgcn_fence(__ATOMIC_ACQUIRE, "agent");     // invalidate stale caches once
    }
    __syncthreads();
}

__device__ __forceinline__ int row2lev(int r) {
    if (r < K_TOP) return 0;
    if (r < 2 * K_TOP) return 1;
    if (r < 2 * K_TOP + N2) return 2;
    if (r < 2 * K_TOP + N2 + N3) return 3;
    return 4;
}

__device__ __forceinline__ void decode_row(const Ptrs& p, int lev, int ai, int r,
                                           float* __restrict__ out,
                                           float4* __restrict__ boxws,
                                           unsigned* __restrict__ rowAi) {
    float4 a4 = ((const float4*)p.anc[lev])[ai];
    float sc = p.cls[lev][ai];
    float4 r4 = *(const float4*)(p.reg[lev] + (size_t)ai * 8);
    float w = a4.z - a4.x + 1.0f, h = a4.w - a4.y + 1.0f;
    float cx = a4.x + 0.5f * w,  cy = a4.y + 0.5f * h;
    float pcx = r4.x * w + cx,   pcy = r4.y * h + cy;
    float pw = expf(r4.z) * w,   ph = expf(r4.w) * h;
    float bx1 = pcx - 0.5f * pw, by1 = pcy - 0.5f * ph;
    float bx2 = pcx + 0.5f * pw - 1.0f, by2 = pcy + 0.5f * ph - 1.0f;
    float* o = out + (size_t)r * 10;
    o[0] = bx1; o[1] = by1; o[2] = bx2; o[3] = by2;
    o[4] = 1.0f / (1.0f + expf(-sc)); o[5] = 1.0f;
    boxws[r] = make_float4(bx1, by1, bx2, by2);
    rowAi[r] = (unsigned)ai;
}

__global__ void __launch_bounds__(NTHR)
k_fused(Ptrs p, const float* __restrict__ gt, const int* __restrict__ numgt,
        State* st, unsigned* __restrict__ hist16,
        unsigned long long* __restrict__ cand,
        unsigned short* __restrict__ part, unsigned* __restrict__ rowAi,
        float4* __restrict__ boxws, float* __restrict__ out) {
    __shared__ float4 sg[MAXGT];       // 32 KiB; aliased as scratch in earlier phases
    __shared__ float  sarea[MAXGT];    // 8 KiB

    unsigned tid  = threadIdx.x;
    unsigned gtid = blockIdx.x * NTHR + tid;
    unsigned* bc = &st->barCnt;
    unsigned* bg = &st->barGen;
    const float* cls0 = p.cls[0];
    const float* cls1 = p.cls[1];

    // ===== Phase A: single-pass 16-bit histogram =====
    for (unsigned e = gtid; e < N0 + N1; e += NBLK * NTHR) {
        int lev = (e < N0) ? 0 : 1;
        unsigned idx = lev ? (e - N0) : e;
        unsigned key = f2ord(lev ? cls1[idx] : cls0[idx]);
        atomicAdd(&hist16[lev * 65536 + (key >> 16)], 1u);
    }
    gbar(bc, bg);

    // ===== Phase B: pick threshold bin (blocks 0 and 1; one level each) =====
    if (blockIdx.x < 2) {
        int lev = blockIdx.x;
        const unsigned* h = hist16 + (size_t)lev * 65536;
        unsigned* A = (unsigned*)sg;          // 512 chunk sums
        unsigned* S = A + 1024;               // scratch: crossT, sufNext, bins[128]
        unsigned base = tid * 128;
        unsigned s = 0;
        for (int k = 0; k < 128; k++) s += h[base + k];
        A[tid] = s;
        __syncthreads();
        // inclusive suffix sum over 512 chunk sums (Hillis-Steele, in place)
        for (int off = 1; off < 512; off <<= 1) {
            unsigned v = A[tid] + ((tid + off < 512) ? A[tid + off] : 0u);
            __syncthreads();
            A[tid] = v;
            __syncthreads();
        }
        unsigned suf = A[tid];
        unsigned sufNext = (tid < 511) ? A[tid + 1] : 0u;
        if (suf >= K_TOP && sufNext < K_TOP) { S[0] = tid; S[1] = sufNext; }
        __syncthreads();
        unsigned ct = S[0];
        if (tid < 128) S[4 + tid] = h[ct * 128 + tid];
        __syncthreads();
        if (tid == 0) {
            unsigned cum = S[1];
            int b = 127;
            for (; b >= 0; b--) { cum += S[4 + b]; if (cum >= K_TOP) break; }
            if (b < 0) b = 0;
            st->prefix[lev] = ((ct << 7) + (unsigned)b) << 16;
        }
    }
    gbar(bc, bg);

    // ===== Phase C: compact keys >= threshold =====
    {
        unsigned T0 = st->prefix[0], T1 = st->prefix[1];
        for (unsigned e = gtid; e < N0 + N1; e += NBLK * NTHR) {
            int lev = (e < N0) ? 0 : 1;
            unsigned idx = lev ? (e - N0) : e;
            unsigned key = f2ord(lev ? cls1[idx] : cls0[idx]);
            unsigned T = lev ? T1 : T0;
            if (key >= T) {
                unsigned slot = atomicAdd(&st->candCount[lev], 1u);
                if (slot < CAP)
                    cand[(size_t)lev * CAP + slot] =
                        ((unsigned long long)key << 32) | (unsigned)(~idx);
            }
        }
    }
    gbar(bc, bg);

    unsigned cnt0 = st->candCount[0]; if (cnt0 > CAP) cnt0 = CAP;
    unsigned cnt1 = st->candCount[1]; if (cnt1 > CAP) cnt1 = CAP;

    // ===== Phase D: partial counting-rank: 256 blocks = lev x 16 ic x 8 jc =====
    {
        int lev = blockIdx.x & 1;
        unsigned ic = (blockIdx.x >> 1) & 15u;
        unsigned jc = blockIdx.x >> 5;
        unsigned cnt = lev ? cnt1 : cnt0;
        unsigned ibase = ic * ICHUNK;
        if (ibase < cnt) {
            unsigned long long ci0, ci1;
            {
                unsigned i0 = ibase + tid, i1 = ibase + tid + NTHR;
                ci0 = (i0 < cnt) ? cand[(size_t)lev * CAP + i0] : 0xFFFFFFFFFFFFFFFFull;
                ci1 = (i1 < cnt) ? cand[(size_t)lev * CAP + i1] : 0xFFFFFFFFFFFFFFFFull;
            }
            unsigned jchunk = (cnt + JSPLIT - 1) / JSPLIT;
            unsigned j0 = jc * jchunk;
            unsigned j1 = j0 + jchunk; if (j1 > cnt) j1 = cnt;
            unsigned rk0 = 0, rk1 = 0;
            unsigned long long* tile = (unsigned long long*)sg;
            for (unsigned base = j0; base < j1; base += NTHR) {
                unsigned j = base + tid;
                tile[tid] = (j < j1) ? cand[(size_t)lev * CAP + j] : 0ull;
                __syncthreads();
                unsigned lim = j1 - base; if (lim > NTHR) lim = NTHR;
                #pragma unroll 4
                for (unsigned t = 0; t < lim; t++) {
                    unsigned long long cj = tile[t];
                    rk0 += (cj > ci0) ? 1u : 0u;
                    rk1 += (cj > ci1) ? 1u : 0u;
                }
                __syncthreads();
            }
            unsigned short* pp = part + ((size_t)(lev * JSPLIT + jc)) * CAP;
            pp[ibase + tid]        = (unsigned short)rk0;
            pp[ibase + tid + NTHR] = (unsigned short)rk1;
        }
    }
    gbar(bc, bg);

    // ===== Phase E: scatter + decode (one item per thread) =====
    {
        unsigned item = gtid;
        if (item < 2 * CAP) {
            int lev = item >> 14;
            unsigned i = item & (CAP - 1);
            unsigned cnt = lev ? cnt1 : cnt0;
            if (i < cnt) {
                unsigned rank = 0;
                #pragma unroll
                for (int s = 0; s < JSPLIT; s++)
                    rank += part[((size_t)(lev * JSPLIT + s)) * CAP + i];
                if (rank < K_TOP) {
                    int ai = (int)~(unsigned)cand[(size_t)lev * CAP + i];
                    decode_row(p, lev, ai, lev * K_TOP + (int)rank, out, boxws, rowAi);
                }
            }
        } else if (item < 2 * CAP + NSMALL) {
            int rr = (int)item - 2 * CAP;
            int lev, ai;
            if (rr < N2)            { lev = 2; ai = rr; }
            else if (rr < N2 + N3)  { lev = 3; ai = rr - N2; }
            else                    { lev = 4; ai = rr - N2 - N3; }
            decode_row(p, lev, ai, 2 * K_TOP + rr, out, boxws, rowAi);
        }
    }
    gbar(bc, bg);

    // ===== Phase F: IoU argmax + targets (2 rows/thread, 8 subs/row) =====
    int ng = *numgt; if (ng > MAXGT) ng = MAXGT;
    for (int g = (int)tid; g < ng; g += NTHR) {
        float x1 = gt[g * 5 + 0], y1 = gt[g * 5 + 1];
        float x2 = gt[g * 5 + 2], y2 = gt[g * 5 + 3];
        sg[g] = make_float4(x1, y1, x2, y2);
        sarea[g] = (x2 - x1 + 1.0f) * (y2 - y1 + 1.0f);
    }
    __syncthreads();

    unsigned u = gtid >> 3;
    int sub = (int)(gtid & 7);
    if (u < HALF) {
        int r0 = (int)u, r1 = (int)u + HALF;
        float4 bA = boxws[r0];
        float4 bB = boxws[r1];
        float areaA = (bA.z - bA.x + 1.0f) * (bA.w - bA.y + 1.0f);
        float areaB = (bB.z - bB.x + 1.0f) * (bB.w - bB.y + 1.0f);
        int chunk = (ng + 7) >> 3;
        int g0 = sub * chunk;
        int g1 = g0 + chunk; if (g1 > ng) g1 = ng; if (g0 > g1) g0 = g1;
        // iou_a > iou_b  <=>  I_a*S_b > I_b*S_a  with S = areaBox + areaGT (I terms cancel)
        float IbA = 0.f, SbA = 1.f; int argA = (sub == 0) ? 0 : 0x7FFFFFFF;
        float IbB = 0.f, SbB = 1.f; int argB = (sub == 0) ? 0 : 0x7FFFFFFF;
        #pragma unroll 2
        for (int g = g0; g < g1; ++g) {
            float4 gb = sg[g];
            float sa = sarea[g];
            float iwA = fminf(bA.z, gb.z) - fmaxf(bA.x, gb.x) + 1.0f; iwA = fmaxf(iwA, 0.f);
            float ihA = fminf(bA.w, gb.w) - fmaxf(bA.y, gb.y) + 1.0f; ihA = fmaxf(ihA, 0.f);
            float IA = iwA * ihA, SA = areaA + sa;
            if (IA * SbA > IbA * SA) { IbA = IA; SbA = SA; argA = g; }
            float iwB = fminf(bB.z, gb.z) - fmaxf(bB.x, gb.x) + 1.0f; iwB = fmaxf(iwB, 0.f);
            float ihB = fminf(bB.w, gb.w) - fmaxf(bB.y, gb.y) + 1.0f; ihB = fmaxf(ihB, 0.f);
            float IB = iwB * ihB, SB = areaB + sa;
            if (IB * SbB > IbB * SB) { IbB = IB; SbB = SB; argB = g; }
        }
        #pragma unroll
        for (int off = 1; off < 8; off <<= 1) {   // max iou, tie -> min index
            float oI = __shfl_xor(IbA, off), oS = __shfl_xor(SbA, off);
            int   oa = __shfl_xor(argA, off);
            float x = oI * SbA, y = IbA * oS;
            if (x > y || (x == y && oa < argA)) { IbA = oI; SbA = oS; argA = oa; }
            oI = __shfl_xor(IbB, off); oS = __shfl_xor(SbB, off);
            oa = __shfl_xor(argB, off);
            x = oI * SbB; y = IbB * oS;
            if (x > y || (x == y && oa < argB)) { IbB = oI; SbB = oS; argB = oa; }
        }
        if (sub < 2) {
            int r  = sub ? r1 : r0;
            int ag = sub ? argB : argA;
            int lev = row2lev(r);
            float4 a4 = ((const float4*)p.anc[lev])[rowAi[r]];
            float w = a4.z - a4.x + 1.0f, h = a4.w - a4.y + 1.0f;
            float cx = a4.x + 0.5f * w,  cy = a4.y + 0.5f * h;
            float4 gb = sg[ag];
            float gw = gb.z - gb.x + 1.0f, gh = gb.w - gb.y + 1.0f;
            float gcx = gb.x + 0.5f * gw, gcy = gb.y + 0.5f * gh;
            float* o = out + (size_t)r * 10;
            o[6] = (gcx - cx) / w;
            o[7] = (gcy - cy) / h;
            o[8] = logf(gw / w);
            o[9] = logf(gh / h);
        }
    }
}

extern "C" void kernel_launch(void* const* d_in, const int* in_sizes, int n_in,
                              void* d_out, int out_size, void* d_ws, size_t ws_size,
                              hipStream_t stream) {
    Ptrs p;
    bool interleaved = (in_sizes[2] == N0 * 8);
    for (int l = 0; l < 5; l++) {
        if (interleaved) {
            p.anc[l] = (const float*)d_in[3 * l + 0];
            p.cls[l] = (const float*)d_in[3 * l + 1];
            p.reg[l] = (const float*)d_in[3 * l + 2];
        } else {
            p.anc[l] = (const float*)d_in[l];
            p.cls[l] = (const float*)d_in[5 + l];
            p.reg[l] = (const float*)d_in[10 + l];
        }
    }
    const float* gt    = (const float*)d_in[15];
    const int*   numgt = (const int*)d_in[16];

    char* ws = (char*)d_ws;
    size_t off = 0;
    State* st = (State*)(ws + off);                              off += 4096;
    unsigned* hist16 = (unsigned*)(ws + off);                    off += (size_t)2 * 65536 * 4;        // 512 KiB
    unsigned long long* cand = (unsigned long long*)(ws + off);  off += (size_t)2 * CAP * 8;          // 256 KiB
    unsigned short* part = (unsigned short*)(ws + off);          off += (size_t)2 * JSPLIT * CAP * 2; // 512 KiB
    unsigned* rowAi = (unsigned*)(ws + off);                     off += (size_t)NROWS * 4;            // 110 KiB
    off = (off + 15) & ~(size_t)15;
    float4* boxws = (float4*)(ws + off);                         off += (size_t)NROWS * 16;           // 439 KiB

    float* out = (float*)d_out;

    k_init<<<dim3(512), dim3(256), 0, stream>>>(st, hist16);
    k_fused<<<dim3(NBLK), dim3(NTHR), 0, stream>>>(p, gt, numgt, st, hist16, cand,
                                                   part, rowAi, boxws, out);
}

// Round 6
// 625.576 us; speedup vs baseline: 1.1175x; 1.0179x over previous
//
#include <hip/hip_runtime.h>
#include <stdint.h>

#define K_TOP 10000
#define CAP   16384            // candidate slack per level (cnt ~ 10.0-10.3k)
#define N0    98304
#define N1    24576
#define N2    6144
#define N3    1536
#define N4    384
#define NSMALL (N2 + N3 + N4)  // 8064
#define NROWS  (2 * K_TOP + NSMALL)   // 28064
#define HALF   (NROWS / 2)            // 14032
#define MAXGT 2048
#define NBLK  256              // == CU count: 1 block/CU, co-resident at dispatch
#define NTHR  512
#define JSPLIT 8
#define ICHUNK 1024            // 16 i-chunks per level

struct State {
    unsigned prefix[2];        // threshold key (top16<<16)
    unsigned candCount[2];
    unsigned barCnt;           // monotonic arrival counter (zeroed by k_init)
};

struct Ptrs { const float* anc[5]; const float* cls[5]; const float* reg[5]; };

__device__ __forceinline__ unsigned f2ord(float f) {
    unsigned u = __float_as_uint(f);
    return (u & 0x80000000u) ? ~u : (u | 0x80000000u);
}

__global__ void k_init(State* st, unsigned* hist16) {
    unsigned g = blockIdx.x * blockDim.x + threadIdx.x;
    if (g < 2u * 65536u) hist16[g] = 0;
    if (g < sizeof(State) / 4) ((unsigned*)st)[g] = 0;
}

// Grid barrier, monotonic-target form.
// KEY gfx950 lesson: the POLL must be an agent-scope atomic RMW (executes at the
// coherence point / MALL). A plain or relaxed-atomic LOAD caches the counter in
// the local XCD L2 and spins on a stale line until random eviction (~130us!).
// Exactly one release fence (wbl2) before arrival publishes this block's plain
// stores; one acquire fence (inv) after release makes peers' stores visible.
__device__ __forceinline__ void gbar(unsigned* cnt, unsigned target) {
    __syncthreads();   // compiler drains vmcnt for all waves before s_barrier
    if (threadIdx.x == 0) {
        __builtin_amdgcn_fence(__ATOMIC_RELEASE, "agent");
        __hip_atomic_fetch_add(cnt, 1u, __ATOMIC_RELAXED, __HIP_MEMORY_SCOPE_AGENT);
        while (__hip_atomic_fetch_add(cnt, 0u, __ATOMIC_RELAXED, __HIP_MEMORY_SCOPE_AGENT) < target)
            __builtin_amdgcn_s_sleep(16);
        __builtin_amdgcn_fence(__ATOMIC_ACQUIRE, "agent");
    }
    __syncthreads();
}

__device__ __forceinline__ int row2lev(int r) {
    if (r < K_TOP) return 0;
    if (r < 2 * K_TOP) return 1;
    if (r < 2 * K_TOP + N2) return 2;
    if (r < 2 * K_TOP + N2 + N3) return 3;
    return 4;
}

__device__ __forceinline__ void decode_row(const Ptrs& p, int lev, int ai, int r,
                                           float* __restrict__ out,
                                           float4* __restrict__ boxws,
                                           unsigned* __restrict__ rowAi) {
    float4 a4 = ((const float4*)p.anc[lev])[ai];
    float sc = p.cls[lev][ai];
    float4 r4 = *(const float4*)(p.reg[lev] + (size_t)ai * 8);
    float w = a4.z - a4.x + 1.0f, h = a4.w - a4.y + 1.0f;
    float cx = a4.x + 0.5f * w,  cy = a4.y + 0.5f * h;
    float pcx = r4.x * w + cx,   pcy = r4.y * h + cy;
    float pw = expf(r4.z) * w,   ph = expf(r4.w) * h;
    float bx1 = pcx - 0.5f * pw, by1 = pcy - 0.5f * ph;
    float bx2 = pcx + 0.5f * pw - 1.0f, by2 = pcy + 0.5f * ph - 1.0f;
    float* o = out + (size_t)r * 10;
    o[0] = bx1; o[1] = by1; o[2] = bx2; o[3] = by2;
    o[4] = 1.0f / (1.0f + expf(-sc)); o[5] = 1.0f;
    boxws[r] = make_float4(bx1, by1, bx2, by2);
    rowAi[r] = (unsigned)ai;
}

__global__ void __launch_bounds__(NTHR)
k_fused(Ptrs p, const float* __restrict__ gt, const int* __restrict__ numgt,
        State* st, unsigned* __restrict__ hist16,
        unsigned long long* __restrict__ cand,
        unsigned short* __restrict__ part, unsigned* __restrict__ rowAi,
        float4* __restrict__ boxws, float* __restrict__ out) {
    __shared__ float4 sg[MAXGT];       // 32 KiB; aliased as scratch in earlier phases
    __shared__ float  sarea[MAXGT];    // 8 KiB

    unsigned tid  = threadIdx.x;
    unsigned gtid = blockIdx.x * NTHR + tid;
    unsigned* bc = &st->barCnt;
    const float* cls0 = p.cls[0];
    const float* cls1 = p.cls[1];

    // ===== Phase A: single-pass 16-bit histogram (device atomics -> MALL) =====
    for (unsigned e = gtid; e < N0 + N1; e += NBLK * NTHR) {
        int lev = (e < N0) ? 0 : 1;
        unsigned idx = lev ? (e - N0) : e;
        unsigned key = f2ord(lev ? cls1[idx] : cls0[idx]);
        atomicAdd(&hist16[lev * 65536 + (key >> 16)], 1u);
    }
    gbar(bc, 1 * NBLK);

    // ===== Phase B: pick threshold bin (blocks 0 and 1; one level each) =====
    if (blockIdx.x < 2) {
        int lev = blockIdx.x;
        const unsigned* h = hist16 + (size_t)lev * 65536;
        unsigned* A = (unsigned*)sg;          // 512 chunk sums
        unsigned* S = A + 1024;               // scratch: crossT, sufNext, bins[128]
        unsigned base = tid * 128;
        unsigned s = 0;
        for (int k = 0; k < 128; k++) s += h[base + k];
        A[tid] = s;
        __syncthreads();
        for (int off = 1; off < 512; off <<= 1) {   // inclusive suffix sum
            unsigned v = A[tid] + ((tid + off < 512) ? A[tid + off] : 0u);
            __syncthreads();
            A[tid] = v;
            __syncthreads();
        }
        unsigned suf = A[tid];
        unsigned sufNext = (tid < 511) ? A[tid + 1] : 0u;
        if (suf >= K_TOP && sufNext < K_TOP) { S[0] = tid; S[1] = sufNext; }
        __syncthreads();
        unsigned ct = S[0];
        if (tid < 128) S[4 + tid] = h[ct * 128 + tid];
        __syncthreads();
        if (tid == 0) {
            unsigned cum = S[1];
            int b = 127;
            for (; b >= 0; b--) { cum += S[4 + b]; if (cum >= K_TOP) break; }
            if (b < 0) b = 0;
            st->prefix[lev] = ((ct << 7) + (unsigned)b) << 16;
        }
    }
    gbar(bc, 2 * NBLK);

    // ===== Phase C: compact keys >= threshold =====
    {
        unsigned T0 = st->prefix[0], T1 = st->prefix[1];
        for (unsigned e = gtid; e < N0 + N1; e += NBLK * NTHR) {
            int lev = (e < N0) ? 0 : 1;
            unsigned idx = lev ? (e - N0) : e;
            unsigned key = f2ord(lev ? cls1[idx] : cls0[idx]);
            unsigned T = lev ? T1 : T0;
            if (key >= T) {
                unsigned slot = atomicAdd(&st->candCount[lev], 1u);
                if (slot < CAP)
                    cand[(size_t)lev * CAP + slot] =
                        ((unsigned long long)key << 32) | (unsigned)(~idx);
            }
        }
    }
    gbar(bc, 3 * NBLK);

    unsigned cnt0 = st->candCount[0]; if (cnt0 > CAP) cnt0 = CAP;
    unsigned cnt1 = st->candCount[1]; if (cnt1 > CAP) cnt1 = CAP;

    // ===== Phase D: partial counting-rank: 256 blocks = lev x 16 ic x 8 jc =====
    {
        int lev = blockIdx.x & 1;
        unsigned ic = (blockIdx.x >> 1) & 15u;
        unsigned jc = blockIdx.x >> 5;
        unsigned cnt = lev ? cnt1 : cnt0;
        unsigned ibase = ic * ICHUNK;
        if (ibase < cnt) {
            unsigned long long ci0, ci1;
            {
                unsigned i0 = ibase + tid, i1 = ibase + tid + NTHR;
                ci0 = (i0 < cnt) ? cand[(size_t)lev * CAP + i0] : 0xFFFFFFFFFFFFFFFFull;
                ci1 = (i1 < cnt) ? cand[(size_t)lev * CAP + i1] : 0xFFFFFFFFFFFFFFFFull;
            }
            unsigned jchunk = (cnt + JSPLIT - 1) / JSPLIT;
            unsigned j0 = jc * jchunk;
            unsigned j1 = j0 + jchunk; if (j1 > cnt) j1 = cnt;
            unsigned rk0 = 0, rk1 = 0;
            unsigned long long* tile = (unsigned long long*)sg;
            for (unsigned base = j0; base < j1; base += NTHR) {
                unsigned j = base + tid;
                tile[tid] = (j < j1) ? cand[(size_t)lev * CAP + j] : 0ull;
                __syncthreads();
                unsigned lim = j1 - base; if (lim > NTHR) lim = NTHR;
                #pragma unroll 4
                for (unsigned t = 0; t < lim; t++) {
                    unsigned long long cj = tile[t];
                    rk0 += (cj > ci0) ? 1u : 0u;
                    rk1 += (cj > ci1) ? 1u : 0u;
                }
                __syncthreads();
            }
            unsigned short* pp = part + ((size_t)(lev * JSPLIT + jc)) * CAP;
            pp[ibase + tid]        = (unsigned short)rk0;
            pp[ibase + tid + NTHR] = (unsigned short)rk1;
        }
    }
    gbar(bc, 4 * NBLK);

    // ===== Phase E: scatter + decode (one item per thread) =====
    {
        unsigned item = gtid;
        if (item < 2 * CAP) {
            int lev = item >> 14;
            unsigned i = item & (CAP - 1);
            unsigned cnt = lev ? cnt1 : cnt0;
            if (i < cnt) {
                unsigned rank = 0;
                #pragma unroll
                for (int s = 0; s < JSPLIT; s++)
                    rank += part[((size_t)(lev * JSPLIT + s)) * CAP + i];
                if (rank < K_TOP) {
                    int ai = (int)~(unsigned)cand[(size_t)lev * CAP + i];
                    decode_row(p, lev, ai, lev * K_TOP + (int)rank, out, boxws, rowAi);
                }
            }
        } else if (item < 2 * CAP + NSMALL) {
            int rr = (int)item - 2 * CAP;
            int lev, ai;
            if (rr < N2)            { lev = 2; ai = rr; }
            else if (rr < N2 + N3)  { lev = 3; ai = rr - N2; }
            else                    { lev = 4; ai = rr - N2 - N3; }
            decode_row(p, lev, ai, 2 * K_TOP + rr, out, boxws, rowAi);
        }
    }
    gbar(bc, 5 * NBLK);

    // ===== Phase F: IoU argmax + targets (2 rows/thread, 8 subs/row) =====
    int ng = *numgt; if (ng > MAXGT) ng = MAXGT;
    for (int g = (int)tid; g < ng; g += NTHR) {
        float x1 = gt[g * 5 + 0], y1 = gt[g * 5 + 1];
        float x2 = gt[g * 5 + 2], y2 = gt[g * 5 + 3];
        sg[g] = make_float4(x1, y1, x2, y2);
        sarea[g] = (x2 - x1 + 1.0f) * (y2 - y1 + 1.0f);
    }
    __syncthreads();

    unsigned u = gtid >> 3;
    int sub = (int)(gtid & 7);
    if (u < HALF) {
        int r0 = (int)u, r1 = (int)u + HALF;
        float4 bA = boxws[r0];
        float4 bB = boxws[r1];
        float areaA = (bA.z - bA.x + 1.0f) * (bA.w - bA.y + 1.0f);
        float areaB = (bB.z - bB.x + 1.0f) * (bB.w - bB.y + 1.0f);
        int chunk = (ng + 7) >> 3;
        int g0 = sub * chunk;
        int g1 = g0 + chunk; if (g1 > ng) g1 = ng; if (g0 > g1) g0 = g1;
        // iou_a > iou_b  <=>  I_a*S_b > I_b*S_a  with S = areaBox + areaGT (I terms cancel)
        float IbA = 0.f, SbA = 1.f; int argA = (sub == 0) ? 0 : 0x7FFFFFFF;
        float IbB = 0.f, SbB = 1.f; int argB = (sub == 0) ? 0 : 0x7FFFFFFF;
        #pragma unroll 2
        for (int g = g0; g < g1; ++g) {
            float4 gb = sg[g];
            float sa = sarea[g];
            float iwA = fminf(bA.z, gb.z) - fmaxf(bA.x, gb.x) + 1.0f; iwA = fmaxf(iwA, 0.f);
            float ihA = fminf(bA.w, gb.w) - fmaxf(bA.y, gb.y) + 1.0f; ihA = fmaxf(ihA, 0.f);
            float IA = iwA * ihA, SA = areaA + sa;
            if (IA * SbA > IbA * SA) { IbA = IA; SbA = SA; argA = g; }
            float iwB = fminf(bB.z, gb.z) - fmaxf(bB.x, gb.x) + 1.0f; iwB = fmaxf(iwB, 0.f);
            float ihB = fminf(bB.w, gb.w) - fmaxf(bB.y, gb.y) + 1.0f; ihB = fmaxf(ihB, 0.f);
            float IB = iwB * ihB, SB = areaB + sa;
            if (IB * SbB > IbB * SB) { IbB = IB; SbB = SB; argB = g; }
        }
        #pragma unroll
        for (int off = 1; off < 8; off <<= 1) {   // max iou, tie -> min index
            float oI = __shfl_xor(IbA, off), oS = __shfl_xor(SbA, off);
            int   oa = __shfl_xor(argA, off);
            float x = oI * SbA, y = IbA * oS;
            if (x > y || (x == y && oa < argA)) { IbA = oI; SbA = oS; argA = oa; }
            oI = __shfl_xor(IbB, off); oS = __shfl_xor(SbB, off);
            oa = __shfl_xor(argB, off);
            x = oI * SbB; y = IbB * oS;
            if (x > y || (x == y && oa < argB)) { IbB = oI; SbB = oS; argB = oa; }
        }
        if (sub < 2) {
            int r  = sub ? r1 : r0;
            int ag = sub ? argB : argA;
            int lev = row2lev(r);
            float4 a4 = ((const float4*)p.anc[lev])[rowAi[r]];
            float w = a4.z - a4.x + 1.0f, h = a4.w - a4.y + 1.0f;
            float cx = a4.x + 0.5f * w,  cy = a4.y + 0.5f * h;
            float4 gb = sg[ag];
            float gw = gb.z - gb.x + 1.0f, gh = gb.w - gb.y + 1.0f;
            float gcx = gb.x + 0.5f * gw, gcy = gb.y + 0.5f * gh;
            float* o = out + (size_t)r * 10;
            o[6] = (gcx - cx) / w;
            o[7] = (gcy - cy) / h;
            o[8] = logf(gw / w);
            o[9] = logf(gh / h);
        }
    }
}

extern "C" void kernel_launch(void* const* d_in, const int* in_sizes, int n_in,
                              void* d_out, int out_size, void* d_ws, size_t ws_size,
                              hipStream_t stream) {
    Ptrs p;
    bool interleaved = (in_sizes[2] == N0 * 8);
    for (int l = 0; l < 5; l++) {
        if (interleaved) {
            p.anc[l] = (const float*)d_in[3 * l + 0];
            p.cls[l] = (const float*)d_in[3 * l + 1];
            p.reg[l] = (const float*)d_in[3 * l + 2];
        } else {
            p.anc[l] = (const float*)d_in[l];
            p.cls[l] = (const float*)d_in[5 + l];
            p.reg[l] = (const float*)d_in[10 + l];
        }
    }
    const float* gt    = (const float*)d_in[15];
    const int*   numgt = (const int*)d_in[16];

    char* ws = (char*)d_ws;
    size_t off = 0;
    State* st = (State*)(ws + off);                              off += 4096;
    unsigned* hist16 = (unsigned*)(ws + off);                    off += (size_t)2 * 65536 * 4;        // 512 KiB
    unsigned long long* cand = (unsigned long long*)(ws + off);  off += (size_t)2 * CAP * 8;          // 256 KiB
    unsigned short* part = (unsigned short*)(ws + off);          off += (size_t)2 * JSPLIT * CAP * 2; // 512 KiB
    unsigned* rowAi = (unsigned*)(ws + off);                     off += (size_t)NROWS * 4;            // 110 KiB
    off = (off + 15) & ~(size_t)15;
    float4* boxws = (float4*)(ws + off);                         off += (size_t)NROWS * 16;           // 439 KiB

    float* out = (float*)d_out;

    k_init<<<dim3(512), dim3(256), 0, stream>>>(st, hist16);
    k_fused<<<dim3(NBLK), dim3(NTHR), 0, stream>>>(p, gt, numgt, st, hist16, cand,
                                                   part, rowAi, boxws, out);
}

// Round 7
// 207.056 us; speedup vs baseline: 3.3762x; 3.0213x over previous
//
#include <hip/hip_runtime.h>
#include <stdint.h>

#define K_TOP 10000
#define CAP   16384            // candidate slack per level (cnt ~ 10.0k + bin spill)
#define N0    98304
#define N1    24576
#define N2    6144
#define N3    1536
#define N4    384
#define NSMALL (N2 + N3 + N4)  // 8064
#define NROWS  (2 * K_TOP + NSMALL)   // 28064
#define MAXGT 2048
#define JSPLIT 16
#define ICHUNK 1024

struct State { unsigned prefix[2]; unsigned candCount[2]; };

struct Ptrs { const float* anc[5]; const float* cls[5]; const float* reg[5]; };

// order-preserving float->uint map (ascending uint == ascending float)
__device__ __forceinline__ unsigned f2ord(float f) {
    unsigned u = __float_as_uint(f);
    return (u & 0x80000000u) ? ~u : (u | 0x80000000u);
}

__global__ void k_init(State* st, unsigned* hist16) {
    unsigned g = blockIdx.x * blockDim.x + threadIdx.x;
    if (g < 2u * 65536u) hist16[g] = 0;
    if (g < sizeof(State) / 4) ((unsigned*)st)[g] = 0;
}

// single-pass 16-bit histogram of both big levels
__global__ void __launch_bounds__(256)
k_hist(const float* __restrict__ cls0, const float* __restrict__ cls1,
       unsigned* __restrict__ hist16) {
    for (unsigned e = blockIdx.x * 256 + threadIdx.x; e < N0 + N1; e += gridDim.x * 256) {
        int lev = (e < N0) ? 0 : 1;
        unsigned idx = lev ? (e - N0) : e;
        unsigned key = f2ord(lev ? cls1[idx] : cls0[idx]);
        atomicAdd(&hist16[lev * 65536 + (key >> 16)], 1u);
    }
}

// threshold pick: 2 blocks (one level each), 512 threads
__global__ void __launch_bounds__(512)
k_pick(State* st, const unsigned* __restrict__ hist16) {
    int lev = blockIdx.x;
    unsigned tid = threadIdx.x;
    const unsigned* h = hist16 + (size_t)lev * 65536;
    __shared__ unsigned A[512];
    __shared__ unsigned S[144];
    unsigned base = tid * 128;
    unsigned s = 0;
    for (int k = 0; k < 128; k++) s += h[base + k];
    A[tid] = s;
    __syncthreads();
    for (int off = 1; off < 512; off <<= 1) {   // inclusive suffix sum
        unsigned v = A[tid] + ((tid + off < 512) ? A[tid + off] : 0u);
        __syncthreads();
        A[tid] = v;
        __syncthreads();
    }
    unsigned suf = A[tid];
    unsigned sufNext = (tid < 511) ? A[tid + 1] : 0u;
    if (suf >= K_TOP && sufNext < K_TOP) { S[0] = tid; S[1] = sufNext; }
    __syncthreads();
    unsigned ct = S[0];
    if (tid < 128) S[4 + tid] = h[ct * 128 + tid];
    __syncthreads();
    if (tid == 0) {
        unsigned cum = S[1];
        int b = 127;
        for (; b >= 0; b--) { cum += S[4 + b]; if (cum >= K_TOP) break; }
        if (b < 0) b = 0;
        st->prefix[lev] = ((ct << 7) + (unsigned)b) << 16;
    }
}

__global__ void __launch_bounds__(256)
k_compact(const float* __restrict__ cls0, const float* __restrict__ cls1,
          State* st, unsigned long long* __restrict__ cand) {
    int lev = blockIdx.y;
    const float* cls = lev ? cls1 : cls0;
    int n = lev ? N1 : N0;
    unsigned T = st->prefix[lev];
    for (int i = blockIdx.x * 256 + threadIdx.x; i < n; i += gridDim.x * 256) {
        unsigned key = f2ord(cls[i]);
        if (key >= T) {
            unsigned slot = atomicAdd(&st->candCount[lev], 1u);
            if (slot < CAP)
                cand[(size_t)lev * CAP + slot] =
                    ((unsigned long long)key << 32) | (unsigned)(~(unsigned)i);
        }
    }
}

// partial counting-rank: grid (16 ic, 16 jc, 2 lev); uniform bounds, 4 keys/thread
__global__ void __launch_bounds__(256)
k_rankpart(State* st, const unsigned long long* __restrict__ cand,
           unsigned short* __restrict__ part) {
    int lev = blockIdx.z;
    unsigned cnt = st->candCount[lev];
    if (cnt > CAP) cnt = CAP;
    unsigned ibase = blockIdx.x * ICHUNK;
    if (ibase >= cnt) return;                 // block-uniform
    unsigned tid = threadIdx.x;
    unsigned long long ci0, ci1, ci2, ci3;
    {
        const unsigned long long* cl = cand + (size_t)lev * CAP + ibase + tid;
        ci0 = (ibase + tid       < cnt) ? cl[0]   : 0xFFFFFFFFFFFFFFFFull;
        ci1 = (ibase + tid + 256 < cnt) ? cl[256] : 0xFFFFFFFFFFFFFFFFull;
        ci2 = (ibase + tid + 512 < cnt) ? cl[512] : 0xFFFFFFFFFFFFFFFFull;
        ci3 = (ibase + tid + 768 < cnt) ? cl[768] : 0xFFFFFFFFFFFFFFFFull;
    }
    unsigned jchunk = (cnt + JSPLIT - 1) / JSPLIT;
    unsigned j0 = blockIdx.y * jchunk;
    unsigned j1 = j0 + jchunk; if (j1 > cnt) j1 = cnt;
    unsigned rk0 = 0, rk1 = 0, rk2 = 0, rk3 = 0;
    __shared__ unsigned long long tile[256];
    for (unsigned base = j0; base < j1; base += 256) {
        unsigned j = base + tid;
        tile[tid] = (j < j1) ? cand[(size_t)lev * CAP + j] : 0ull;
        __syncthreads();
        unsigned lim = j1 - base; if (lim > 256u) lim = 256u;   // block-uniform
        #pragma unroll 4
        for (unsigned t = 0; t < lim; t++) {
            unsigned long long cj = tile[t];
            rk0 += (cj > ci0) ? 1u : 0u;
            rk1 += (cj > ci1) ? 1u : 0u;
            rk2 += (cj > ci2) ? 1u : 0u;
            rk3 += (cj > ci3) ? 1u : 0u;
        }
        __syncthreads();
    }
    unsigned short* pp = part + ((size_t)(lev * JSPLIT + blockIdx.y)) * CAP + ibase + tid;
    pp[0]   = (unsigned short)rk0;
    pp[256] = (unsigned short)rk1;
    pp[512] = (unsigned short)rk2;
    pp[768] = (unsigned short)rk3;
}

__global__ void __launch_bounds__(256)
k_scatter(State* st, const unsigned long long* __restrict__ cand,
          const unsigned short* __restrict__ part, unsigned* __restrict__ selIdx) {
    int lev = blockIdx.y;
    unsigned cnt = st->candCount[lev];
    if (cnt > CAP) cnt = CAP;
    unsigned i = blockIdx.x * 256 + threadIdx.x;
    if (i >= cnt) return;
    unsigned rank = 0;
    #pragma unroll
    for (int s = 0; s < JSPLIT; s++)
        rank += part[((size_t)(lev * JSPLIT + s)) * CAP + i];
    if (rank < K_TOP)
        selIdx[lev * K_TOP + rank] = ~(unsigned)cand[(size_t)lev * CAP + i];
}

// Fused decode + IoU argmax + targets. 8 lanes per row:
//   sub==0 decodes box (exp/sigmoid), writes out[0..5], shfl-broadcasts box;
//   all 8 lanes scan 250 GT each (division-free comparator); shfl argmax;
//   sub==0 writes targets from registers it already holds.
__global__ void __launch_bounds__(256)
k_ioudecode(Ptrs p, const unsigned* __restrict__ selIdx,
            const float* __restrict__ gt, const int* __restrict__ numgt,
            float* __restrict__ out) {
    __shared__ float4 sg[MAXGT];
    __shared__ float  sarea[MAXGT];
    int ng = *numgt; if (ng > MAXGT) ng = MAXGT;
    for (int g = (int)threadIdx.x; g < ng; g += 256) {
        float x1 = gt[g * 5 + 0], y1 = gt[g * 5 + 1];
        float x2 = gt[g * 5 + 2], y2 = gt[g * 5 + 3];
        sg[g] = make_float4(x1, y1, x2, y2);
        sarea[g] = (x2 - x1 + 1.0f) * (y2 - y1 + 1.0f);
    }
    __syncthreads();

    unsigned gid = blockIdx.x * 256 + threadIdx.x;
    int r = (int)(gid >> 3);
    int sub = (int)(gid & 7);
    if (r >= NROWS) return;

    // ---- decode on sub==0 ----
    float bx1 = 0.f, by1 = 0.f, bx2 = 0.f, by2 = 0.f;
    float w = 1.f, h = 1.f, cx = 0.f, cy = 0.f;
    if (sub == 0) {
        int lev, ai;
        if (r < 2 * K_TOP) {
            lev = (r < K_TOP) ? 0 : 1;
            ai = (int)selIdx[r];
        } else {
            int rr = r - 2 * K_TOP;
            if (rr < N2)           { lev = 2; ai = rr; }
            else if (rr < N2 + N3) { lev = 3; ai = rr - N2; }
            else                   { lev = 4; ai = rr - N2 - N3; }
        }
        float4 a4 = ((const float4*)p.anc[lev])[ai];
        float sc = p.cls[lev][ai];
        float4 r4 = *(const float4*)(p.reg[lev] + (size_t)ai * 8);
        w = a4.z - a4.x + 1.0f;  h = a4.w - a4.y + 1.0f;
        cx = a4.x + 0.5f * w;    cy = a4.y + 0.5f * h;
        float pcx = r4.x * w + cx, pcy = r4.y * h + cy;
        float pw = expf(r4.z) * w, ph = expf(r4.w) * h;
        bx1 = pcx - 0.5f * pw;   by1 = pcy - 0.5f * ph;
        bx2 = pcx + 0.5f * pw - 1.0f;
        by2 = pcy + 0.5f * ph - 1.0f;
        float* o = out + (size_t)r * 10;
        o[0] = bx1; o[1] = by1; o[2] = bx2; o[3] = by2;
        o[4] = 1.0f / (1.0f + expf(-sc));
        o[5] = 1.0f;
    }
    // broadcast box from the sub==0 lane of this 8-lane group
    int lane = (int)(threadIdx.x & 63u);
    int src = lane & ~7;
    bx1 = __shfl(bx1, src, 64);
    by1 = __shfl(by1, src, 64);
    bx2 = __shfl(bx2, src, 64);
    by2 = __shfl(by2, src, 64);
    float areaA = (bx2 - bx1 + 1.0f) * (by2 - by1 + 1.0f);

    int chunk = (ng + 7) >> 3;
    int g0 = sub * chunk;
    int g1 = g0 + chunk; if (g1 > ng) g1 = ng; if (g0 > g1) g0 = g1;
    // iou_a > iou_b  <=>  I_a*S_b > I_b*S_a  with S = areaBox + areaGT (I terms cancel)
    float Ib = 0.f, Sb = 1.f;
    int arg = (sub == 0) ? 0 : 0x7FFFFFFF;
    for (int g = g0; g < g1; ++g) {
        float4 gb = sg[g];
        float iw = fminf(bx2, gb.z) - fmaxf(bx1, gb.x) + 1.0f; iw = fmaxf(iw, 0.f);
        float ih = fminf(by2, gb.w) - fmaxf(by1, gb.y) + 1.0f; ih = fmaxf(ih, 0.f);
        float I = iw * ih, S = areaA + sarea[g];
        if (I * Sb > Ib * S) { Ib = I; Sb = S; arg = g; }
    }
    #pragma unroll
    for (int off = 1; off < 8; off <<= 1) {   // max iou, tie -> min index
        float oI = __shfl_xor(Ib, off), oS = __shfl_xor(Sb, off);
        int   oa = __shfl_xor(arg, off);
        float x = oI * Sb, y = Ib * oS;
        if (x > y || (x == y && oa < arg)) { Ib = oI; Sb = oS; arg = oa; }
    }
    if (sub != 0) return;
    if (arg >= ng) arg = 0;

    float4 gb = sg[arg];
    float gw = gb.z - gb.x + 1.0f, gh = gb.w - gb.y + 1.0f;
    float gcx = gb.x + 0.5f * gw,  gcy = gb.y + 0.5f * gh;
    float* o = out + (size_t)r * 10;
    o[6] = (gcx - cx) / w;
    o[7] = (gcy - cy) / h;
    o[8] = logf(gw / w);
    o[9] = logf(gh / h);
}

extern "C" void kernel_launch(void* const* d_in, const int* in_sizes, int n_in,
                              void* d_out, int out_size, void* d_ws, size_t ws_size,
                              hipStream_t stream) {
    Ptrs p;
    bool interleaved = (in_sizes[2] == N0 * 8);
    for (int l = 0; l < 5; l++) {
        if (interleaved) {
            p.anc[l] = (const float*)d_in[3 * l + 0];
            p.cls[l] = (const float*)d_in[3 * l + 1];
            p.reg[l] = (const float*)d_in[3 * l + 2];
        } else {
            p.anc[l] = (const float*)d_in[l];
            p.cls[l] = (const float*)d_in[5 + l];
            p.reg[l] = (const float*)d_in[10 + l];
        }
    }
    const float* gt    = (const float*)d_in[15];
    const int*   numgt = (const int*)d_in[16];

    char* ws = (char*)d_ws;
    size_t off = 0;
    State* st = (State*)(ws + off);                              off += 4096;
    unsigned* hist16 = (unsigned*)(ws + off);                    off += (size_t)2 * 65536 * 4;        // 512 KiB
    unsigned long long* cand = (unsigned long long*)(ws + off);  off += (size_t)2 * CAP * 8;          // 256 KiB
    unsigned short* part = (unsigned short*)(ws + off);          off += (size_t)2 * JSPLIT * CAP * 2; // 1 MiB
    unsigned* selIdx = (unsigned*)(ws + off);                    off += (size_t)2 * K_TOP * 4;        // 80 KiB

    float* out = (float*)d_out;

    k_init<<<dim3(512), dim3(256), 0, stream>>>(st, hist16);
    k_hist<<<dim3(256), dim3(256), 0, stream>>>(p.cls[0], p.cls[1], hist16);
    k_pick<<<dim3(2), dim3(512), 0, stream>>>(st, hist16);
    k_compact<<<dim3(96, 2), dim3(256), 0, stream>>>(p.cls[0], p.cls[1], st, cand);
    k_rankpart<<<dim3(16, JSPLIT, 2), dim3(256), 0, stream>>>(st, cand, part);
    k_scatter<<<dim3(CAP / 256, 2), dim3(256), 0, stream>>>(st, cand, part, selIdx);
    k_ioudecode<<<dim3((NROWS * 8) / 256), dim3(256), 0, stream>>>(p, selIdx, gt, numgt, out);
}

// Round 8
// 131.024 us; speedup vs baseline: 5.3353x; 1.5803x over previous
//
#include <hip/hip_runtime.h>
#include <stdint.h>

#define K_TOP 10000
#define CAP   16384            // candidate slack per level (cnt <= K + threshold-bin spill ~1.3k)
#define N0    98304
#define N1    24576
#define N2    6144
#define N3    1536
#define N4    384
#define NSMALL (N2 + N3 + N4)  // 8064
#define NROWS  (2 * K_TOP + NSMALL)   // 28064
#define MAXGT 2048
#define JSPLIT 16
#define ICHUNK 1024
#define NSLICE 128             // hist8 blocks

struct State { unsigned prefix[2]; unsigned candCount[2]; };

struct Ptrs { const float* anc[5]; const float* cls[5]; const float* reg[5]; };

// order-preserving float->uint map (ascending uint == ascending float)
__device__ __forceinline__ unsigned f2ord(float f) {
    unsigned u = __float_as_uint(f);
    return (u & 0x80000000u) ? ~u : (u | 0x80000000u);
}

// Pass-0: top-8-bit histogram, per-wave LDS privatization, per-block slice output.
// No global atomics, no pre-zeroed global state.
__global__ void __launch_bounds__(512)
k_hist8(const float* __restrict__ cls0, const float* __restrict__ cls1,
        unsigned* __restrict__ slices) {
    __shared__ unsigned h[8][512];       // [wave][lev*256 + bin], 16 KiB
    unsigned tid = threadIdx.x;
    for (unsigned i = tid; i < 8u * 512u; i += 512u) ((unsigned*)h)[i] = 0;
    __syncthreads();
    unsigned wave = tid >> 6;
    const unsigned NQ0 = N0 / 4, NQ1 = N1 / 4;
    for (unsigned q = blockIdx.x * 512u + tid; q < NQ0 + NQ1; q += NSLICE * 512u) {
        int lev = (q < NQ0) ? 0 : 1;
        const float4* src = lev ? (const float4*)cls1 : (const float4*)cls0;
        float4 v = src[lev ? (q - NQ0) : q];
        unsigned base = (unsigned)lev * 256u;
        atomicAdd(&h[wave][base + (f2ord(v.x) >> 24)], 1u);
        atomicAdd(&h[wave][base + (f2ord(v.y) >> 24)], 1u);
        atomicAdd(&h[wave][base + (f2ord(v.z) >> 24)], 1u);
        atomicAdd(&h[wave][base + (f2ord(v.w) >> 24)], 1u);
    }
    __syncthreads();
    unsigned s = 0;
    #pragma unroll
    for (int w2 = 0; w2 < 8; w2++) s += h[w2][tid];
    slices[blockIdx.x * 512u + tid] = s;
}

// 2 blocks (one level each): sum slices -> top byte; re-read level in-block to
// histogram the 2nd byte (wave-private LDS) -> exact 16-bit threshold.
// Also zeroes candCount (replaces k_init).
__global__ void __launch_bounds__(512)
k_pick2(const float* __restrict__ cls0, const float* __restrict__ cls1,
        const unsigned* __restrict__ slices, State* st) {
    int lev = blockIdx.x;
    unsigned tid = threadIdx.x;
    __shared__ unsigned sfx[256];
    __shared__ unsigned h2[8][256];     // 8 KiB
    __shared__ unsigned sd[2];          // [0]=crossing bin, [1]=remK
    if (tid < 256) {
        unsigned s = 0;
        for (int k = 0; k < NSLICE; k++) s += slices[(unsigned)k * 512u + (unsigned)lev * 256u + tid];
        sfx[tid] = s;
    }
    __syncthreads();
    for (int off = 1; off < 256; off <<= 1) {     // inclusive suffix sum
        unsigned v = 0;
        if (tid < 256) v = sfx[tid] + ((tid + off < 256) ? sfx[tid + off] : 0u);
        __syncthreads();
        if (tid < 256) sfx[tid] = v;
        __syncthreads();
    }
    if (tid < 256) {
        unsigned suf = sfx[tid];
        unsigned sufN = (tid < 255) ? sfx[tid + 1] : 0u;
        if (suf >= K_TOP && sufN < K_TOP) { sd[0] = tid; sd[1] = K_TOP - sufN; }
    }
    for (unsigned i = tid; i < 8u * 256u; i += 512u) ((unsigned*)h2)[i] = 0;
    __syncthreads();
    unsigned tb = sd[0], remK = sd[1];
    unsigned wave = tid >> 6;
    const float4* src = lev ? (const float4*)cls1 : (const float4*)cls0;
    unsigned nq = (lev ? N1 : N0) / 4;
    for (unsigned q = tid; q < nq; q += 512u) {
        float4 v = src[q];
        unsigned k0 = f2ord(v.x), k1 = f2ord(v.y), k2 = f2ord(v.z), k3 = f2ord(v.w);
        if ((k0 >> 24) == tb) atomicAdd(&h2[wave][(k0 >> 16) & 255u], 1u);
        if ((k1 >> 24) == tb) atomicAdd(&h2[wave][(k1 >> 16) & 255u], 1u);
        if ((k2 >> 24) == tb) atomicAdd(&h2[wave][(k2 >> 16) & 255u], 1u);
        if ((k3 >> 24) == tb) atomicAdd(&h2[wave][(k3 >> 16) & 255u], 1u);
    }
    __syncthreads();
    if (tid < 256) {
        unsigned s = 0;
        #pragma unroll
        for (int w2 = 0; w2 < 8; w2++) s += h2[w2][tid];
        sfx[tid] = s;
    }
    __syncthreads();
    for (int off = 1; off < 256; off <<= 1) {
        unsigned v = 0;
        if (tid < 256) v = sfx[tid] + ((tid + off < 256) ? sfx[tid + off] : 0u);
        __syncthreads();
        if (tid < 256) sfx[tid] = v;
        __syncthreads();
    }
    if (tid < 256) {
        unsigned suf = sfx[tid];
        unsigned sufN = (tid < 255) ? sfx[tid + 1] : 0u;
        if (suf >= remK && sufN < remK) sd[0] = tid;
    }
    __syncthreads();
    if (tid == 0) {
        st->prefix[lev] = ((tb << 8) | sd[0]) << 16;
        st->candCount[lev] = 0;
    }
}

__global__ void __launch_bounds__(256)
k_compact(const float* __restrict__ cls0, const float* __restrict__ cls1,
          State* st, unsigned long long* __restrict__ cand) {
    int lev = blockIdx.y;
    const float* cls = lev ? cls1 : cls0;
    int n = lev ? N1 : N0;
    unsigned T = st->prefix[lev];
    for (int i = blockIdx.x * 256 + threadIdx.x; i < n; i += gridDim.x * 256) {
        unsigned key = f2ord(cls[i]);
        if (key >= T) {
            unsigned slot = atomicAdd(&st->candCount[lev], 1u);
            if (slot < CAP)
                cand[(size_t)lev * CAP + slot] =
                    ((unsigned long long)key << 32) | (unsigned)(~(unsigned)i);
        }
    }
}

// partial counting-rank: grid (16 ic, 16 jc, 2 lev); uniform bounds, 4 keys/thread
__global__ void __launch_bounds__(256)
k_rankpart(State* st, const unsigned long long* __restrict__ cand,
           unsigned short* __restrict__ part) {
    int lev = blockIdx.z;
    unsigned cnt = st->candCount[lev];
    if (cnt > CAP) cnt = CAP;
    unsigned ibase = blockIdx.x * ICHUNK;
    if (ibase >= cnt) return;                 // block-uniform
    unsigned tid = threadIdx.x;
    unsigned long long ci0, ci1, ci2, ci3;
    {
        const unsigned long long* cl = cand + (size_t)lev * CAP + ibase + tid;
        ci0 = (ibase + tid       < cnt) ? cl[0]   : 0xFFFFFFFFFFFFFFFFull;
        ci1 = (ibase + tid + 256 < cnt) ? cl[256] : 0xFFFFFFFFFFFFFFFFull;
        ci2 = (ibase + tid + 512 < cnt) ? cl[512] : 0xFFFFFFFFFFFFFFFFull;
        ci3 = (ibase + tid + 768 < cnt) ? cl[768] : 0xFFFFFFFFFFFFFFFFull;
    }
    unsigned jchunk = (cnt + JSPLIT - 1) / JSPLIT;
    unsigned j0 = blockIdx.y * jchunk;
    unsigned j1 = j0 + jchunk; if (j1 > cnt) j1 = cnt;
    unsigned rk0 = 0, rk1 = 0, rk2 = 0, rk3 = 0;
    __shared__ unsigned long long tile[256];
    for (unsigned base = j0; base < j1; base += 256) {
        unsigned j = base + tid;
        tile[tid] = (j < j1) ? cand[(size_t)lev * CAP + j] : 0ull;
        __syncthreads();
        unsigned lim = j1 - base; if (lim > 256u) lim = 256u;   // block-uniform
        #pragma unroll 4
        for (unsigned t = 0; t < lim; t++) {
            unsigned long long cj = tile[t];
            rk0 += (cj > ci0) ? 1u : 0u;
            rk1 += (cj > ci1) ? 1u : 0u;
            rk2 += (cj > ci2) ? 1u : 0u;
            rk3 += (cj > ci3) ? 1u : 0u;
        }
        __syncthreads();
    }
    unsigned short* pp = part + ((size_t)(lev * JSPLIT + blockIdx.y)) * CAP + ibase + tid;
    pp[0]   = (unsigned short)rk0;
    pp[256] = (unsigned short)rk1;
    pp[512] = (unsigned short)rk2;
    pp[768] = (unsigned short)rk3;
}

__global__ void __launch_bounds__(256)
k_scatter(State* st, const unsigned long long* __restrict__ cand,
          const unsigned short* __restrict__ part, unsigned* __restrict__ selIdx) {
    int lev = blockIdx.y;
    unsigned cnt = st->candCount[lev];
    if (cnt > CAP) cnt = CAP;
    unsigned i = blockIdx.x * 256 + threadIdx.x;
    if (i >= cnt) return;
    unsigned rank = 0;
    #pragma unroll
    for (int s = 0; s < JSPLIT; s++)
        rank += part[((size_t)(lev * JSPLIT + s)) * CAP + i];
    if (rank < K_TOP)
        selIdx[lev * K_TOP + rank] = ~(unsigned)cand[(size_t)lev * CAP + i];
}

// Fused decode + IoU argmax + targets. 8 lanes per row.
__global__ void __launch_bounds__(256)
k_ioudecode(Ptrs p, const unsigned* __restrict__ selIdx,
            const float* __restrict__ gt, const int* __restrict__ numgt,
            float* __restrict__ out) {
    __shared__ float4 sg[MAXGT];
    __shared__ float  sarea[MAXGT];
    int ng = *numgt; if (ng > MAXGT) ng = MAXGT;
    for (int g = (int)threadIdx.x; g < ng; g += 256) {
        float x1 = gt[g * 5 + 0], y1 = gt[g * 5 + 1];
        float x2 = gt[g * 5 + 2], y2 = gt[g * 5 + 3];
        sg[g] = make_float4(x1, y1, x2, y2);
        sarea[g] = (x2 - x1 + 1.0f) * (y2 - y1 + 1.0f);
    }
    __syncthreads();

    unsigned gid = blockIdx.x * 256 + threadIdx.x;
    int r = (int)(gid >> 3);
    int sub = (int)(gid & 7);
    if (r >= NROWS) return;

    // ---- decode on sub==0 ----
    float bx1 = 0.f, by1 = 0.f, bx2 = 0.f, by2 = 0.f;
    float w = 1.f, h = 1.f, cx = 0.f, cy = 0.f;
    if (sub == 0) {
        int lev, ai;
        if (r < 2 * K_TOP) {
            lev = (r < K_TOP) ? 0 : 1;
            ai = (int)selIdx[r];
        } else {
            int rr = r - 2 * K_TOP;
            if (rr < N2)           { lev = 2; ai = rr; }
            else if (rr < N2 + N3) { lev = 3; ai = rr - N2; }
            else                   { lev = 4; ai = rr - N2 - N3; }
        }
        float4 a4 = ((const float4*)p.anc[lev])[ai];
        float sc = p.cls[lev][ai];
        float4 r4 = *(const float4*)(p.reg[lev] + (size_t)ai * 8);
        w = a4.z - a4.x + 1.0f;  h = a4.w - a4.y + 1.0f;
        cx = a4.x + 0.5f * w;    cy = a4.y + 0.5f * h;
        float pcx = r4.x * w + cx, pcy = r4.y * h + cy;
        float pw = expf(r4.z) * w, ph = expf(r4.w) * h;
        bx1 = pcx - 0.5f * pw;   by1 = pcy - 0.5f * ph;
        bx2 = pcx + 0.5f * pw - 1.0f;
        by2 = pcy + 0.5f * ph - 1.0f;
        float* o = out + (size_t)r * 10;
        o[0] = bx1; o[1] = by1; o[2] = bx2; o[3] = by2;
        o[4] = 1.0f / (1.0f + expf(-sc));
        o[5] = 1.0f;
    }
    // broadcast box from the sub==0 lane of this 8-lane group
    int lane = (int)(threadIdx.x & 63u);
    int src = lane & ~7;
    bx1 = __shfl(bx1, src, 64);
    by1 = __shfl(by1, src, 64);
    bx2 = __shfl(bx2, src, 64);
    by2 = __shfl(by2, src, 64);
    float areaA = (bx2 - bx1 + 1.0f) * (by2 - by1 + 1.0f);

    int chunk = (ng + 7) >> 3;
    int g0 = sub * chunk;
    int g1 = g0 + chunk; if (g1 > ng) g1 = ng; if (g0 > g1) g0 = g1;
    // iou_a > iou_b  <=>  I_a*S_b > I_b*S_a  with S = areaBox + areaGT (I terms cancel)
    float Ib = 0.f, Sb = 1.f;
    int arg = (sub == 0) ? 0 : 0x7FFFFFFF;
    for (int g = g0; g < g1; ++g) {
        float4 gb = sg[g];
        float iw = fminf(bx2, gb.z) - fmaxf(bx1, gb.x) + 1.0f; iw = fmaxf(iw, 0.f);
        float ih = fminf(by2, gb.w) - fmaxf(by1, gb.y) + 1.0f; ih = fmaxf(ih, 0.f);
        float I = iw * ih, S = areaA + sarea[g];
        if (I * Sb > Ib * S) { Ib = I; Sb = S; arg = g; }
    }
    #pragma unroll
    for (int off = 1; off < 8; off <<= 1) {   // max iou, tie -> min index
        float oI = __shfl_xor(Ib, off), oS = __shfl_xor(Sb, off);
        int   oa = __shfl_xor(arg, off);
        float x = oI * Sb, y = Ib * oS;
        if (x > y || (x == y && oa < arg)) { Ib = oI; Sb = oS; arg = oa; }
    }
    if (sub != 0) return;
    if (arg >= ng) arg = 0;

    float4 gb = sg[arg];
    float gw = gb.z - gb.x + 1.0f, gh = gb.w - gb.y + 1.0f;
    float gcx = gb.x + 0.5f * gw,  gcy = gb.y + 0.5f * gh;
    float* o = out + (size_t)r * 10;
    o[6] = (gcx - cx) / w;
    o[7] = (gcy - cy) / h;
    o[8] = logf(gw / w);
    o[9] = logf(gh / h);
}

extern "C" void kernel_launch(void* const* d_in, const int* in_sizes, int n_in,
                              void* d_out, int out_size, void* d_ws, size_t ws_size,
                              hipStream_t stream) {
    Ptrs p;
    bool interleaved = (in_sizes[2] == N0 * 8);
    for (int l = 0; l < 5; l++) {
        if (interleaved) {
            p.anc[l] = (const float*)d_in[3 * l + 0];
            p.cls[l] = (const float*)d_in[3 * l + 1];
            p.reg[l] = (const float*)d_in[3 * l + 2];
        } else {
            p.anc[l] = (const float*)d_in[l];
            p.cls[l] = (const float*)d_in[5 + l];
            p.reg[l] = (const float*)d_in[10 + l];
        }
    }
    const float* gt    = (const float*)d_in[15];
    const int*   numgt = (const int*)d_in[16];

    char* ws = (char*)d_ws;
    size_t off = 0;
    State* st = (State*)(ws + off);                              off += 4096;
    unsigned* slices = (unsigned*)(ws + off);                    off += (size_t)NSLICE * 512 * 4;     // 256 KiB
    unsigned long long* cand = (unsigned long long*)(ws + off);  off += (size_t)2 * CAP * 8;          // 256 KiB
    unsigned short* part = (unsigned short*)(ws + off);          off += (size_t)2 * JSPLIT * CAP * 2; // 1 MiB
    unsigned* selIdx = (unsigned*)(ws + off);                    off += (size_t)2 * K_TOP * 4;        // 80 KiB

    float* out = (float*)d_out;

    k_hist8<<<dim3(NSLICE), dim3(512), 0, stream>>>(p.cls[0], p.cls[1], slices);
    k_pick2<<<dim3(2), dim3(512), 0, stream>>>(p.cls[0], p.cls[1], slices, st);
    k_compact<<<dim3(96, 2), dim3(256), 0, stream>>>(p.cls[0], p.cls[1], st, cand);
    k_rankpart<<<dim3(16, JSPLIT, 2), dim3(256), 0, stream>>>(st, cand, part);
    k_scatter<<<dim3(CAP / 256, 2), dim3(256), 0, stream>>>(st, cand, part, selIdx);
    k_ioudecode<<<dim3((NROWS * 8) / 256), dim3(256), 0, stream>>>(p, selIdx, gt, numgt, out);
}

// Round 9
// 107.553 us; speedup vs baseline: 6.4996x; 1.2182x over previous
//
#include <hip/hip_runtime.h>
#include <stdint.h>

#define K_TOP 10000
#define CAP   16384            // candidate slack per level (cnt <= K + threshold-bin spill)
#define N0    98304
#define N1    24576
#define N2    6144
#define N3    1536
#define N4    384
#define NSMALL (N2 + N3 + N4)  // 8064
#define NROWS  (2 * K_TOP + NSMALL)   // 28064
#define MAXGT 2048
#define JSPLIT 16
#define ICHUNK 1024
#define NSLICE 128             // hist8 blocks
#define ISUB   16              // sub-lanes per row in ioudecode

struct State { unsigned prefix[2]; unsigned candCount[2]; };

struct Ptrs { const float* anc[5]; const float* cls[5]; const float* reg[5]; };

// order-preserving float->uint map (ascending uint == ascending float)
__device__ __forceinline__ unsigned f2ord(float f) {
    unsigned u = __float_as_uint(f);
    return (u & 0x80000000u) ? ~u : (u | 0x80000000u);
}

// Pass-0: top-8-bit histogram, per-wave LDS privatization, per-block slice output.
__global__ void __launch_bounds__(512)
k_hist8(const float* __restrict__ cls0, const float* __restrict__ cls1,
        unsigned* __restrict__ slices) {
    __shared__ unsigned h[8][512];       // [wave][lev*256 + bin], 16 KiB
    unsigned tid = threadIdx.x;
    for (unsigned i = tid; i < 8u * 512u; i += 512u) ((unsigned*)h)[i] = 0;
    __syncthreads();
    unsigned wave = tid >> 6;
    const unsigned NQ0 = N0 / 4, NQ1 = N1 / 4;
    for (unsigned q = blockIdx.x * 512u + tid; q < NQ0 + NQ1; q += NSLICE * 512u) {
        int lev = (q < NQ0) ? 0 : 1;
        const float4* src = lev ? (const float4*)cls1 : (const float4*)cls0;
        float4 v = src[lev ? (q - NQ0) : q];
        unsigned base = (unsigned)lev * 256u;
        atomicAdd(&h[wave][base + (f2ord(v.x) >> 24)], 1u);
        atomicAdd(&h[wave][base + (f2ord(v.y) >> 24)], 1u);
        atomicAdd(&h[wave][base + (f2ord(v.z) >> 24)], 1u);
        atomicAdd(&h[wave][base + (f2ord(v.w) >> 24)], 1u);
    }
    __syncthreads();
    unsigned s = 0;
    #pragma unroll
    for (int w2 = 0; w2 < 8; w2++) s += h[w2][tid];
    slices[blockIdx.x * 512u + tid] = s;
}

// 2 blocks (one level each): sum slices -> top byte; re-read level in-block to
// histogram the 2nd byte (wave-private LDS) -> exact 16-bit threshold.
// Also zeroes candCount.
__global__ void __launch_bounds__(512)
k_pick2(const float* __restrict__ cls0, const float* __restrict__ cls1,
        const unsigned* __restrict__ slices, State* st) {
    int lev = blockIdx.x;
    unsigned tid = threadIdx.x;
    __shared__ unsigned sfx[256];
    __shared__ unsigned h2[8][256];     // 8 KiB
    __shared__ unsigned sd[2];          // [0]=crossing bin, [1]=remK
    if (tid < 256) {
        unsigned s = 0;
        for (int k = 0; k < NSLICE; k++) s += slices[(unsigned)k * 512u + (unsigned)lev * 256u + tid];
        sfx[tid] = s;
    }
    __syncthreads();
    for (int off = 1; off < 256; off <<= 1) {     // inclusive suffix sum
        unsigned v = 0;
        if (tid < 256) v = sfx[tid] + ((tid + off < 256) ? sfx[tid + off] : 0u);
        __syncthreads();
        if (tid < 256) sfx[tid] = v;
        __syncthreads();
    }
    if (tid < 256) {
        unsigned suf = sfx[tid];
        unsigned sufN = (tid < 255) ? sfx[tid + 1] : 0u;
        if (suf >= K_TOP && sufN < K_TOP) { sd[0] = tid; sd[1] = K_TOP - sufN; }
    }
    for (unsigned i = tid; i < 8u * 256u; i += 512u) ((unsigned*)h2)[i] = 0;
    __syncthreads();
    unsigned tb = sd[0], remK = sd[1];
    unsigned wave = tid >> 6;
    const float4* src = lev ? (const float4*)cls1 : (const float4*)cls0;
    unsigned nq = (lev ? N1 : N0) / 4;
    for (unsigned q = tid; q < nq; q += 512u) {
        float4 v = src[q];
        unsigned k0 = f2ord(v.x), k1 = f2ord(v.y), k2 = f2ord(v.z), k3 = f2ord(v.w);
        if ((k0 >> 24) == tb) atomicAdd(&h2[wave][(k0 >> 16) & 255u], 1u);
        if ((k1 >> 24) == tb) atomicAdd(&h2[wave][(k1 >> 16) & 255u], 1u);
        if ((k2 >> 24) == tb) atomicAdd(&h2[wave][(k2 >> 16) & 255u], 1u);
        if ((k3 >> 24) == tb) atomicAdd(&h2[wave][(k3 >> 16) & 255u], 1u);
    }
    __syncthreads();
    if (tid < 256) {
        unsigned s = 0;
        #pragma unroll
        for (int w2 = 0; w2 < 8; w2++) s += h2[w2][tid];
        sfx[tid] = s;
    }
    __syncthreads();
    for (int off = 1; off < 256; off <<= 1) {
        unsigned v = 0;
        if (tid < 256) v = sfx[tid] + ((tid + off < 256) ? sfx[tid + off] : 0u);
        __syncthreads();
        if (tid < 256) sfx[tid] = v;
        __syncthreads();
    }
    if (tid < 256) {
        unsigned suf = sfx[tid];
        unsigned sufN = (tid < 255) ? sfx[tid + 1] : 0u;
        if (suf >= remK && sufN < remK) sd[0] = tid;
    }
    __syncthreads();
    if (tid == 0) {
        st->prefix[lev] = ((tb << 8) | sd[0]) << 16;
        st->candCount[lev] = 0;
    }
}

// Compact with block-aggregated slot allocation: ONE global RMW per block
// (same-address global atomic returns serialize at the coherence point).
// Order within cand is nondeterministic but the rank pass makes order exact.
__global__ void __launch_bounds__(256)
k_compact(const float* __restrict__ cls0, const float* __restrict__ cls1,
          State* st, unsigned long long* __restrict__ cand) {
    int lev = blockIdx.y;
    const float* cls = lev ? cls1 : cls0;
    unsigned n = lev ? N1 : N0;
    unsigned T = st->prefix[lev];
    unsigned stride = gridDim.x * 256u;
    unsigned iters = (n + stride - 1u) / stride;          // 4 (lev0) / 1 (lev1)
    unsigned long long l0 = 0, l1 = 0, l2 = 0, l3 = 0;    // static-indexed stash
    unsigned c = 0;
    unsigned i = blockIdx.x * 256u + threadIdx.x;
    for (unsigned t = 0; t < iters; t++, i += stride) {
        if (i < n) {
            unsigned key = f2ord(cls[i]);
            if (key >= T) {
                unsigned long long v = ((unsigned long long)key << 32) | (unsigned)(~i);
                if (c == 0) l0 = v; else if (c == 1) l1 = v;
                else if (c == 2) l2 = v; else l3 = v;
                c++;
            }
        }
    }
    __shared__ unsigned lcnt, gbase;
    if (threadIdx.x == 0) lcnt = 0;
    __syncthreads();
    unsigned ls = 0;
    if (c) ls = atomicAdd(&lcnt, c);
    __syncthreads();
    if (threadIdx.x == 0) gbase = atomicAdd(&st->candCount[lev], lcnt);
    __syncthreads();
    unsigned b = gbase + ls;
    unsigned long long* cl = cand + (size_t)lev * CAP;
    if (c > 0 && b + 0 < CAP) cl[b + 0] = l0;
    if (c > 1 && b + 1 < CAP) cl[b + 1] = l1;
    if (c > 2 && b + 2 < CAP) cl[b + 2] = l2;
    if (c > 3 && b + 3 < CAP) cl[b + 3] = l3;
}

// partial counting-rank: grid (16 ic, 16 jc, 2 lev); uniform bounds, 4 keys/thread
__global__ void __launch_bounds__(256)
k_rankpart(State* st, const unsigned long long* __restrict__ cand,
           unsigned short* __restrict__ part) {
    int lev = blockIdx.z;
    unsigned cnt = st->candCount[lev];
    if (cnt > CAP) cnt = CAP;
    unsigned ibase = blockIdx.x * ICHUNK;
    if (ibase >= cnt) return;                 // block-uniform
    unsigned tid = threadIdx.x;
    unsigned long long ci0, ci1, ci2, ci3;
    {
        const unsigned long long* cl = cand + (size_t)lev * CAP + ibase + tid;
        ci0 = (ibase + tid       < cnt) ? cl[0]   : 0xFFFFFFFFFFFFFFFFull;
        ci1 = (ibase + tid + 256 < cnt) ? cl[256] : 0xFFFFFFFFFFFFFFFFull;
        ci2 = (ibase + tid + 512 < cnt) ? cl[512] : 0xFFFFFFFFFFFFFFFFull;
        ci3 = (ibase + tid + 768 < cnt) ? cl[768] : 0xFFFFFFFFFFFFFFFFull;
    }
    unsigned jchunk = (cnt + JSPLIT - 1) / JSPLIT;
    unsigned j0 = blockIdx.y * jchunk;
    unsigned j1 = j0 + jchunk; if (j1 > cnt) j1 = cnt;
    unsigned rk0 = 0, rk1 = 0, rk2 = 0, rk3 = 0;
    __shared__ unsigned long long tile[256];
    for (unsigned base = j0; base < j1; base += 256) {
        unsigned j = base + tid;
        tile[tid] = (j < j1) ? cand[(size_t)lev * CAP + j] : 0ull;
        __syncthreads();
        unsigned lim = j1 - base; if (lim > 256u) lim = 256u;   // block-uniform
        #pragma unroll 4
        for (unsigned t = 0; t < lim; t++) {
            unsigned long long cj = tile[t];
            rk0 += (cj > ci0) ? 1u : 0u;
            rk1 += (cj > ci1) ? 1u : 0u;
            rk2 += (cj > ci2) ? 1u : 0u;
            rk3 += (cj > ci3) ? 1u : 0u;
        }
        __syncthreads();
    }
    unsigned short* pp = part + ((size_t)(lev * JSPLIT + blockIdx.y)) * CAP + ibase + tid;
    pp[0]   = (unsigned short)rk0;
    pp[256] = (unsigned short)rk1;
    pp[512] = (unsigned short)rk2;
    pp[768] = (unsigned short)rk3;
}

__global__ void __launch_bounds__(256)
k_scatter(State* st, const unsigned long long* __restrict__ cand,
          const unsigned short* __restrict__ part, unsigned* __restrict__ selIdx) {
    int lev = blockIdx.y;
    unsigned cnt = st->candCount[lev];
    if (cnt > CAP) cnt = CAP;
    unsigned i = blockIdx.x * 256 + threadIdx.x;
    if (i >= cnt) return;
    unsigned rank = 0;
    #pragma unroll
    for (int s = 0; s < JSPLIT; s++)
        rank += part[((size_t)(lev * JSPLIT + s)) * CAP + i];
    if (rank < K_TOP)
        selIdx[lev * K_TOP + rank] = ~(unsigned)cand[(size_t)lev * CAP + i];
}

// Fused decode + IoU argmax + targets. 16 lanes per row (125 GTs each).
__global__ void __launch_bounds__(512)
k_ioudecode(Ptrs p, const unsigned* __restrict__ selIdx,
            const float* __restrict__ gt, const int* __restrict__ numgt,
            float* __restrict__ out) {
    __shared__ float4 sg[MAXGT];
    __shared__ float  sarea[MAXGT];
    int ng = *numgt; if (ng > MAXGT) ng = MAXGT;
    for (int g = (int)threadIdx.x; g < ng; g += 512) {
        float x1 = gt[g * 5 + 0], y1 = gt[g * 5 + 1];
        float x2 = gt[g * 5 + 2], y2 = gt[g * 5 + 3];
        sg[g] = make_float4(x1, y1, x2, y2);
        sarea[g] = (x2 - x1 + 1.0f) * (y2 - y1 + 1.0f);
    }
    __syncthreads();

    unsigned gid = blockIdx.x * 512 + threadIdx.x;
    int r = (int)(gid >> 4);
    int sub = (int)(gid & 15);
    if (r >= NROWS) return;

    // ---- decode on sub==0 ----
    float bx1 = 0.f, by1 = 0.f, bx2 = 0.f, by2 = 0.f;
    float w = 1.f, h = 1.f, cx = 0.f, cy = 0.f;
    if (sub == 0) {
        int lev, ai;
        if (r < 2 * K_TOP) {
            lev = (r < K_TOP) ? 0 : 1;
            ai = (int)selIdx[r];
        } else {
            int rr = r - 2 * K_TOP;
            if (rr < N2)           { lev = 2; ai = rr; }
            else if (rr < N2 + N3) { lev = 3; ai = rr - N2; }
            else                   { lev = 4; ai = rr - N2 - N3; }
        }
        float4 a4 = ((const float4*)p.anc[lev])[ai];
        float sc = p.cls[lev][ai];
        float4 r4 = *(const float4*)(p.reg[lev] + (size_t)ai * 8);
        w = a4.z - a4.x + 1.0f;  h = a4.w - a4.y + 1.0f;
        cx = a4.x + 0.5f * w;    cy = a4.y + 0.5f * h;
        float pcx = r4.x * w + cx, pcy = r4.y * h + cy;
        float pw = expf(r4.z) * w, ph = expf(r4.w) * h;
        bx1 = pcx - 0.5f * pw;   by1 = pcy - 0.5f * ph;
        bx2 = pcx + 0.5f * pw - 1.0f;
        by2 = pcy + 0.5f * ph - 1.0f;
        float* o = out + (size_t)r * 10;
        o[0] = bx1; o[1] = by1; o[2] = bx2; o[3] = by2;
        o[4] = 1.0f / (1.0f + expf(-sc));
        o[5] = 1.0f;
    }
    // broadcast box from the sub==0 lane of this 16-lane group
    int lane = (int)(threadIdx.x & 63u);
    int src = lane & ~15;
    bx1 = __shfl(bx1, src, 64);
    by1 = __shfl(by1, src, 64);
    bx2 = __shfl(bx2, src, 64);
    by2 = __shfl(by2, src, 64);
    float areaA = (bx2 - bx1 + 1.0f) * (by2 - by1 + 1.0f);

    int chunk = (ng + ISUB - 1) / ISUB;
    int g0 = sub * chunk;
    int g1 = g0 + chunk; if (g1 > ng) g1 = ng; if (g0 > g1) g0 = g1;
    // iou_a > iou_b  <=>  I_a*S_b > I_b*S_a  with S = areaBox + areaGT (I terms cancel)
    float Ib = 0.f, Sb = 1.f;
    int arg = (sub == 0) ? 0 : 0x7FFFFFFF;
    for (int g = g0; g < g1; ++g) {
        float4 gb = sg[g];
        float iw = fminf(bx2, gb.z) - fmaxf(bx1, gb.x) + 1.0f; iw = fmaxf(iw, 0.f);
        float ih = fminf(by2, gb.w) - fmaxf(by1, gb.y) + 1.0f; ih = fmaxf(ih, 0.f);
        float I = iw * ih, S = areaA + sarea[g];
        if (I * Sb > Ib * S) { Ib = I; Sb = S; arg = g; }
    }
    #pragma unroll
    for (int off = 1; off < 16; off <<= 1) {   // max iou, tie -> min index
        float oI = __shfl_xor(Ib, off), oS = __shfl_xor(Sb, off);
        int   oa = __shfl_xor(arg, off);
        float x = oI * Sb, y = Ib * oS;
        if (x > y || (x == y && oa < arg)) { Ib = oI; Sb = oS; arg = oa; }
    }
    if (sub != 0) return;
    if (arg >= ng) arg = 0;

    float4 gb = sg[arg];
    float gw = gb.z - gb.x + 1.0f, gh = gb.w - gb.y + 1.0f;
    float gcx = gb.x + 0.5f * gw,  gcy = gb.y + 0.5f * gh;
    float* o = out + (size_t)r * 10;
    o[6] = (gcx - cx) / w;
    o[7] = (gcy - cy) / h;
    o[8] = logf(gw / w);
    o[9] = logf(gh / h);
}

extern "C" void kernel_launch(void* const* d_in, const int* in_sizes, int n_in,
                              void* d_out, int out_size, void* d_ws, size_t ws_size,
                              hipStream_t stream) {
    Ptrs p;
    bool interleaved = (in_sizes[2] == N0 * 8);
    for (int l = 0; l < 5; l++) {
        if (interleaved) {
            p.anc[l] = (const float*)d_in[3 * l + 0];
            p.cls[l] = (const float*)d_in[3 * l + 1];
            p.reg[l] = (const float*)d_in[3 * l + 2];
        } else {
            p.anc[l] = (const float*)d_in[l];
            p.cls[l] = (const float*)d_in[5 + l];
            p.reg[l] = (const float*)d_in[10 + l];
        }
    }
    const float* gt    = (const float*)d_in[15];
    const int*   numgt = (const int*)d_in[16];

    char* ws = (char*)d_ws;
    size_t off = 0;
    State* st = (State*)(ws + off);                              off += 4096;
    unsigned* slices = (unsigned*)(ws + off);                    off += (size_t)NSLICE * 512 * 4;     // 256 KiB
    unsigned long long* cand = (unsigned long long*)(ws + off);  off += (size_t)2 * CAP * 8;          // 256 KiB
    unsigned short* part = (unsigned short*)(ws + off);          off += (size_t)2 * JSPLIT * CAP * 2; // 1 MiB
    unsigned* selIdx = (unsigned*)(ws + off);                    off += (size_t)2 * K_TOP * 4;        // 80 KiB

    float* out = (float*)d_out;

    k_hist8<<<dim3(NSLICE), dim3(512), 0, stream>>>(p.cls[0], p.cls[1], slices);
    k_pick2<<<dim3(2), dim3(512), 0, stream>>>(p.cls[0], p.cls[1], slices, st);
    k_compact<<<dim3(96, 2), dim3(256), 0, stream>>>(p.cls[0], p.cls[1], st, cand);
    k_rankpart<<<dim3(16, JSPLIT, 2), dim3(256), 0, stream>>>(st, cand, part);
    k_scatter<<<dim3(CAP / 256, 2), dim3(256), 0, stream>>>(st, cand, part, selIdx);
    k_ioudecode<<<dim3((NROWS * ISUB) / 512), dim3(512), 0, stream>>>(p, selIdx, gt, numgt, out);
}

// Round 10
// 105.320 us; speedup vs baseline: 6.6374x; 1.0212x over previous
//
#include <hip/hip_runtime.h>
#include <stdint.h>

#define K_TOP 10000
#define CAP   16384            // candidate slack per level (cnt <= K + threshold-bin spill)
#define N0    98304
#define N1    24576
#define N2    6144
#define N3    1536
#define N4    384
#define NSMALL (N2 + N3 + N4)  // 8064
#define NROWS  (2 * K_TOP + NSMALL)   // 28064
#define Q4     (NROWS / 4)            // 7016 (exact)
#define MAXGT 2048
#define JSPLIT 16
#define ICHUNK 1024
#define NSLICE 128             // hist8 blocks
#define ISUB   16              // lanes per row-quad in ioudecode

struct State { unsigned prefix[2]; unsigned candCount[2]; };

struct Ptrs { const float* anc[5]; const float* cls[5]; const float* reg[5]; };

// order-preserving float->uint map (ascending uint == ascending float)
__device__ __forceinline__ unsigned f2ord(float f) {
    unsigned u = __float_as_uint(f);
    return (u & 0x80000000u) ? ~u : (u | 0x80000000u);
}

// Pass-0: top-8-bit histogram, per-wave LDS privatization, per-block slice output.
__global__ void __launch_bounds__(512)
k_hist8(const float* __restrict__ cls0, const float* __restrict__ cls1,
        unsigned* __restrict__ slices) {
    __shared__ unsigned h[8][512];       // [wave][lev*256 + bin], 16 KiB
    unsigned tid = threadIdx.x;
    for (unsigned i = tid; i < 8u * 512u; i += 512u) ((unsigned*)h)[i] = 0;
    __syncthreads();
    unsigned wave = tid >> 6;
    const unsigned NQ0 = N0 / 4, NQ1 = N1 / 4;
    for (unsigned q = blockIdx.x * 512u + tid; q < NQ0 + NQ1; q += NSLICE * 512u) {
        int lev = (q < NQ0) ? 0 : 1;
        const float4* src = lev ? (const float4*)cls1 : (const float4*)cls0;
        float4 v = src[lev ? (q - NQ0) : q];
        unsigned base = (unsigned)lev * 256u;
        atomicAdd(&h[wave][base + (f2ord(v.x) >> 24)], 1u);
        atomicAdd(&h[wave][base + (f2ord(v.y) >> 24)], 1u);
        atomicAdd(&h[wave][base + (f2ord(v.z) >> 24)], 1u);
        atomicAdd(&h[wave][base + (f2ord(v.w) >> 24)], 1u);
    }
    __syncthreads();
    unsigned s = 0;
    #pragma unroll
    for (int w2 = 0; w2 < 8; w2++) s += h[w2][tid];
    slices[blockIdx.x * 512u + tid] = s;
}

// 2 blocks (one level each): sum slices -> top byte; re-read level in-block to
// histogram the 2nd byte (wave-private LDS) -> exact 16-bit threshold.
// Also zeroes candCount.
__global__ void __launch_bounds__(512)
k_pick2(const float* __restrict__ cls0, const float* __restrict__ cls1,
        const unsigned* __restrict__ slices, State* st) {
    int lev = blockIdx.x;
    unsigned tid = threadIdx.x;
    __shared__ unsigned sfx[256];
    __shared__ unsigned h2[8][256];     // 8 KiB
    __shared__ unsigned sd[2];          // [0]=crossing bin, [1]=remK
    if (tid < 256) {
        unsigned s = 0;
        for (int k = 0; k < NSLICE; k++) s += slices[(unsigned)k * 512u + (unsigned)lev * 256u + tid];
        sfx[tid] = s;
    }
    __syncthreads();
    for (int off = 1; off < 256; off <<= 1) {     // inclusive suffix sum
        unsigned v = 0;
        if (tid < 256) v = sfx[tid] + ((tid + off < 256) ? sfx[tid + off] : 0u);
        __syncthreads();
        if (tid < 256) sfx[tid] = v;
        __syncthreads();
    }
    if (tid < 256) {
        unsigned suf = sfx[tid];
        unsigned sufN = (tid < 255) ? sfx[tid + 1] : 0u;
        if (suf >= K_TOP && sufN < K_TOP) { sd[0] = tid; sd[1] = K_TOP - sufN; }
    }
    for (unsigned i = tid; i < 8u * 256u; i += 512u) ((unsigned*)h2)[i] = 0;
    __syncthreads();
    unsigned tb = sd[0], remK = sd[1];
    unsigned wave = tid >> 6;
    const float4* src = lev ? (const float4*)cls1 : (const float4*)cls0;
    unsigned nq = (lev ? N1 : N0) / 4;
    for (unsigned q = tid; q < nq; q += 512u) {
        float4 v = src[q];
        unsigned k0 = f2ord(v.x), k1 = f2ord(v.y), k2 = f2ord(v.z), k3 = f2ord(v.w);
        if ((k0 >> 24) == tb) atomicAdd(&h2[wave][(k0 >> 16) & 255u], 1u);
        if ((k1 >> 24) == tb) atomicAdd(&h2[wave][(k1 >> 16) & 255u], 1u);
        if ((k2 >> 24) == tb) atomicAdd(&h2[wave][(k2 >> 16) & 255u], 1u);
        if ((k3 >> 24) == tb) atomicAdd(&h2[wave][(k3 >> 16) & 255u], 1u);
    }
    __syncthreads();
    if (tid < 256) {
        unsigned s = 0;
        #pragma unroll
        for (int w2 = 0; w2 < 8; w2++) s += h2[w2][tid];
        sfx[tid] = s;
    }
    __syncthreads();
    for (int off = 1; off < 256; off <<= 1) {
        unsigned v = 0;
        if (tid < 256) v = sfx[tid] + ((tid + off < 256) ? sfx[tid + off] : 0u);
        __syncthreads();
        if (tid < 256) sfx[tid] = v;
        __syncthreads();
    }
    if (tid < 256) {
        unsigned suf = sfx[tid];
        unsigned sufN = (tid < 255) ? sfx[tid + 1] : 0u;
        if (suf >= remK && sufN < remK) sd[0] = tid;
    }
    __syncthreads();
    if (tid == 0) {
        st->prefix[lev] = ((tb << 8) | sd[0]) << 16;
        st->candCount[lev] = 0;
    }
}

// Compact with block-aggregated slot allocation: ONE global RMW per block.
// Order within cand is nondeterministic but the rank pass makes order exact.
__global__ void __launch_bounds__(256)
k_compact(const float* __restrict__ cls0, const float* __restrict__ cls1,
          State* st, unsigned long long* __restrict__ cand) {
    int lev = blockIdx.y;
    const float* cls = lev ? cls1 : cls0;
    unsigned n = lev ? N1 : N0;
    unsigned T = st->prefix[lev];
    unsigned stride = gridDim.x * 256u;
    unsigned iters = (n + stride - 1u) / stride;
    unsigned long long l0 = 0, l1 = 0, l2 = 0, l3 = 0;    // static-indexed stash
    unsigned c = 0;
    unsigned i = blockIdx.x * 256u + threadIdx.x;
    for (unsigned t = 0; t < iters; t++, i += stride) {
        if (i < n) {
            unsigned key = f2ord(cls[i]);
            if (key >= T) {
                unsigned long long v = ((unsigned long long)key << 32) | (unsigned)(~i);
                if (c == 0) l0 = v; else if (c == 1) l1 = v;
                else if (c == 2) l2 = v; else l3 = v;
                c++;
            }
        }
    }
    __shared__ unsigned lcnt, gbase;
    if (threadIdx.x == 0) lcnt = 0;
    __syncthreads();
    unsigned ls = 0;
    if (c) ls = atomicAdd(&lcnt, c);
    __syncthreads();
    if (threadIdx.x == 0) gbase = atomicAdd(&st->candCount[lev], lcnt);
    __syncthreads();
    unsigned b = gbase + ls;
    unsigned long long* cl = cand + (size_t)lev * CAP;
    if (c > 0 && b + 0 < CAP) cl[b + 0] = l0;
    if (c > 1 && b + 1 < CAP) cl[b + 1] = l1;
    if (c > 2 && b + 2 < CAP) cl[b + 2] = l2;
    if (c > 3 && b + 3 < CAP) cl[b + 3] = l3;
}

// partial counting-rank: grid (16 ic, 16 jc, 2 lev); uniform bounds, 4 keys/thread
__global__ void __launch_bounds__(256)
k_rankpart(State* st, const unsigned long long* __restrict__ cand,
           unsigned short* __restrict__ part) {
    int lev = blockIdx.z;
    unsigned cnt = st->candCount[lev];
    if (cnt > CAP) cnt = CAP;
    unsigned ibase = blockIdx.x * ICHUNK;
    if (ibase >= cnt) return;                 // block-uniform
    unsigned tid = threadIdx.x;
    unsigned long long ci0, ci1, ci2, ci3;
    {
        const unsigned long long* cl = cand + (size_t)lev * CAP + ibase + tid;
        ci0 = (ibase + tid       < cnt) ? cl[0]   : 0xFFFFFFFFFFFFFFFFull;
        ci1 = (ibase + tid + 256 < cnt) ? cl[256] : 0xFFFFFFFFFFFFFFFFull;
        ci2 = (ibase + tid + 512 < cnt) ? cl[512] : 0xFFFFFFFFFFFFFFFFull;
        ci3 = (ibase + tid + 768 < cnt) ? cl[768] : 0xFFFFFFFFFFFFFFFFull;
    }
    unsigned jchunk = (cnt + JSPLIT - 1) / JSPLIT;
    unsigned j0 = blockIdx.y * jchunk;
    unsigned j1 = j0 + jchunk; if (j1 > cnt) j1 = cnt;
    unsigned rk0 = 0, rk1 = 0, rk2 = 0, rk3 = 0;
    __shared__ unsigned long long tile[256];
    for (unsigned base = j0; base < j1; base += 256) {
        unsigned j = base + tid;
        tile[tid] = (j < j1) ? cand[(size_t)lev * CAP + j] : 0ull;
        __syncthreads();
        unsigned lim = j1 - base; if (lim > 256u) lim = 256u;   // block-uniform
        #pragma unroll 4
        for (unsigned t = 0; t < lim; t++) {
            unsigned long long cj = tile[t];
            rk0 += (cj > ci0) ? 1u : 0u;
            rk1 += (cj > ci1) ? 1u : 0u;
            rk2 += (cj > ci2) ? 1u : 0u;
            rk3 += (cj > ci3) ? 1u : 0u;
        }
        __syncthreads();
    }
    unsigned short* pp = part + ((size_t)(lev * JSPLIT + blockIdx.y)) * CAP + ibase + tid;
    pp[0]   = (unsigned short)rk0;
    pp[256] = (unsigned short)rk1;
    pp[512] = (unsigned short)rk2;
    pp[768] = (unsigned short)rk3;
}

__global__ void __launch_bounds__(256)
k_scatter(State* st, const unsigned long long* __restrict__ cand,
          const unsigned short* __restrict__ part, unsigned* __restrict__ selIdx) {
    int lev = blockIdx.y;
    unsigned cnt = st->candCount[lev];
    if (cnt > CAP) cnt = CAP;
    unsigned i = blockIdx.x * 256 + threadIdx.x;
    if (i >= cnt) return;
    unsigned rank = 0;
    #pragma unroll
    for (int s = 0; s < JSPLIT; s++)
        rank += part[((size_t)(lev * JSPLIT + s)) * CAP + i];
    if (rank < K_TOP)
        selIdx[lev * K_TOP + rank] = ~(unsigned)cand[(size_t)lev * CAP + i];
}

// Fused decode + IoU argmax + targets. 16-lane group owns 4 rows (u + j*Q4);
// one GT read per iteration serves 4 pairs per lane (LDS-pipe amortization).
__global__ void __launch_bounds__(512)
k_ioudecode(Ptrs p, const unsigned* __restrict__ selIdx,
            const float* __restrict__ gt, const int* __restrict__ numgt,
            float* __restrict__ out) {
    __shared__ float4 sg[MAXGT];
    __shared__ float  sarea[MAXGT];
    int ng = *numgt; if (ng > MAXGT) ng = MAXGT;
    for (int g = (int)threadIdx.x; g < ng; g += 512) {
        float x1 = gt[g * 5 + 0], y1 = gt[g * 5 + 1];
        float x2 = gt[g * 5 + 2], y2 = gt[g * 5 + 3];
        sg[g] = make_float4(x1, y1, x2, y2);
        sarea[g] = (x2 - x1 + 1.0f) * (y2 - y1 + 1.0f);
    }
    __syncthreads();

    unsigned gid = blockIdx.x * 512u + threadIdx.x;
    unsigned u = gid >> 4;
    int sub = (int)(gid & 15u);
    if (u >= (unsigned)Q4) return;    // exits in whole 16-lane groups

    // ---- decode: lanes sub<4 each decode row u + sub*Q4, keep anchor geometry ----
    float dbx1 = 0.f, dby1 = 0.f, dbx2 = 0.f, dby2 = 0.f;
    float dw = 1.f, dh = 1.f, dcx = 0.f, dcy = 0.f;
    if (sub < 4) {
        int r = (int)u + sub * Q4;
        int lev, ai;
        if (r < 2 * K_TOP) {
            lev = (r < K_TOP) ? 0 : 1;
            ai = (int)selIdx[r];
        } else {
            int rr = r - 2 * K_TOP;
            if (rr < N2)           { lev = 2; ai = rr; }
            else if (rr < N2 + N3) { lev = 3; ai = rr - N2; }
            else                   { lev = 4; ai = rr - N2 - N3; }
        }
        float4 a4 = ((const float4*)p.anc[lev])[ai];
        float sc = p.cls[lev][ai];
        float4 r4 = *(const float4*)(p.reg[lev] + (size_t)ai * 8);
        dw = a4.z - a4.x + 1.0f;  dh = a4.w - a4.y + 1.0f;
        dcx = a4.x + 0.5f * dw;   dcy = a4.y + 0.5f * dh;
        float pcx = r4.x * dw + dcx, pcy = r4.y * dh + dcy;
        float pw = expf(r4.z) * dw,  ph = expf(r4.w) * dh;
        dbx1 = pcx - 0.5f * pw;   dby1 = pcy - 0.5f * ph;
        dbx2 = pcx + 0.5f * pw - 1.0f;
        dby2 = pcy + 0.5f * ph - 1.0f;
        float* o = out + (size_t)r * 10;
        o[0] = dbx1; o[1] = dby1; o[2] = dbx2; o[3] = dby2;
        o[4] = 1.0f / (1.0f + expf(-sc));
        o[5] = 1.0f;
    }
    int base = (int)(threadIdx.x & 63u) & ~15;
    // broadcast the 4 decoded boxes to all 16 lanes of the group
    float x10 = __shfl(dbx1, base + 0, 64), y10 = __shfl(dby1, base + 0, 64);
    float x20 = __shfl(dbx2, base + 0, 64), y20 = __shfl(dby2, base + 0, 64);
    float x11 = __shfl(dbx1, base + 1, 64), y11 = __shfl(dby1, base + 1, 64);
    float x21 = __shfl(dbx2, base + 1, 64), y21 = __shfl(dby2, base + 1, 64);
    float x12 = __shfl(dbx1, base + 2, 64), y12 = __shfl(dby1, base + 2, 64);
    float x22 = __shfl(dbx2, base + 2, 64), y22 = __shfl(dby2, base + 2, 64);
    float x13 = __shfl(dbx1, base + 3, 64), y13 = __shfl(dby1, base + 3, 64);
    float x23 = __shfl(dbx2, base + 3, 64), y23 = __shfl(dby2, base + 3, 64);
    float A0 = (x20 - x10 + 1.0f) * (y20 - y10 + 1.0f);
    float A1 = (x21 - x11 + 1.0f) * (y21 - y11 + 1.0f);
    float A2 = (x22 - x12 + 1.0f) * (y22 - y12 + 1.0f);
    float A3 = (x23 - x13 + 1.0f) * (y23 - y13 + 1.0f);

    int chunk = (ng + ISUB - 1) / ISUB;
    int g0 = sub * chunk;
    int g1 = g0 + chunk; if (g1 > ng) g1 = ng; if (g0 > g1) g0 = g1;
    // iou_a > iou_b  <=>  I_a*S_b > I_b*S_a  with S = areaBox + areaGT (I terms cancel)
    float I0 = 0.f, S0 = 1.f; int a0 = (sub == 0) ? 0 : 0x7FFFFFFF;
    float I1 = 0.f, S1 = 1.f; int a1 = (sub == 0) ? 0 : 0x7FFFFFFF;
    float I2 = 0.f, S2 = 1.f; int a2 = (sub == 0) ? 0 : 0x7FFFFFFF;
    float I3 = 0.f, S3 = 1.f; int a3 = (sub == 0) ? 0 : 0x7FFFFFFF;
    for (int g = g0; g < g1; ++g) {
        float4 gb = sg[g];
        float sa = sarea[g];
        float iw, ih, I, S;
        iw = fminf(x20, gb.z) - fmaxf(x10, gb.x) + 1.0f; iw = fmaxf(iw, 0.f);
        ih = fminf(y20, gb.w) - fmaxf(y10, gb.y) + 1.0f; ih = fmaxf(ih, 0.f);
        I = iw * ih; S = A0 + sa;
        if (I * S0 > I0 * S) { I0 = I; S0 = S; a0 = g; }
        iw = fminf(x21, gb.z) - fmaxf(x11, gb.x) + 1.0f; iw = fmaxf(iw, 0.f);
        ih = fminf(y21, gb.w) - fmaxf(y11, gb.y) + 1.0f; ih = fmaxf(ih, 0.f);
        I = iw * ih; S = A1 + sa;
        if (I * S1 > I1 * S) { I1 = I; S1 = S; a1 = g; }
        iw = fminf(x22, gb.z) - fmaxf(x12, gb.x) + 1.0f; iw = fmaxf(iw, 0.f);
        ih = fminf(y22, gb.w) - fmaxf(y12, gb.y) + 1.0f; ih = fmaxf(ih, 0.f);
        I = iw * ih; S = A2 + sa;
        if (I * S2 > I2 * S) { I2 = I; S2 = S; a2 = g; }
        iw = fminf(x23, gb.z) - fmaxf(x13, gb.x) + 1.0f; iw = fmaxf(iw, 0.f);
        ih = fminf(y23, gb.w) - fmaxf(y13, gb.y) + 1.0f; ih = fmaxf(ih, 0.f);
        I = iw * ih; S = A3 + sa;
        if (I * S3 > I3 * S) { I3 = I; S3 = S; a3 = g; }
    }
    // reduce across 16 lanes: max iou, tie -> min index (== sequential first-max)
    #pragma unroll
    for (int off = 1; off < 16; off <<= 1) {
        float oI, oS, x, y; int oa;
        oI = __shfl_xor(I0, off); oS = __shfl_xor(S0, off); oa = __shfl_xor(a0, off);
        x = oI * S0; y = I0 * oS;
        if (x > y || (x == y && oa < a0)) { I0 = oI; S0 = oS; a0 = oa; }
        oI = __shfl_xor(I1, off); oS = __shfl_xor(S1, off); oa = __shfl_xor(a1, off);
        x = oI * S1; y = I1 * oS;
        if (x > y || (x == y && oa < a1)) { I1 = oI; S1 = oS; a1 = oa; }
        oI = __shfl_xor(I2, off); oS = __shfl_xor(S2, off); oa = __shfl_xor(a2, off);
        x = oI * S2; y = I2 * oS;
        if (x > y || (x == y && oa < a2)) { I2 = oI; S2 = oS; a2 = oa; }
        oI = __shfl_xor(I3, off); oS = __shfl_xor(S3, off); oa = __shfl_xor(a3, off);
        x = oI * S3; y = I3 * oS;
        if (x > y || (x == y && oa < a3)) { I3 = oI; S3 = oS; a3 = oa; }
    }
    if (sub < 4) {
        int arg = (sub == 0) ? a0 : (sub == 1) ? a1 : (sub == 2) ? a2 : a3;
        if (arg >= ng) arg = 0;
        float4 gb = sg[arg];
        float gw = gb.z - gb.x + 1.0f, gh = gb.w - gb.y + 1.0f;
        float gcx = gb.x + 0.5f * gw,  gcy = gb.y + 0.5f * gh;
        int r = (int)u + sub * Q4;
        float* o = out + (size_t)r * 10;
        o[6] = (gcx - dcx) / dw;
        o[7] = (gcy - dcy) / dh;
        o[8] = logf(gw / dw);
        o[9] = logf(gh / dh);
    }
}

extern "C" void kernel_launch(void* const* d_in, const int* in_sizes, int n_in,
                              void* d_out, int out_size, void* d_ws, size_t ws_size,
                              hipStream_t stream) {
    Ptrs p;
    bool interleaved = (in_sizes[2] == N0 * 8);
    for (int l = 0; l < 5; l++) {
        if (interleaved) {
            p.anc[l] = (const float*)d_in[3 * l + 0];
            p.cls[l] = (const float*)d_in[3 * l + 1];
            p.reg[l] = (const float*)d_in[3 * l + 2];
        } else {
            p.anc[l] = (const float*)d_in[l];
            p.cls[l] = (const float*)d_in[5 + l];
            p.reg[l] = (const float*)d_in[10 + l];
        }
    }
    const float* gt    = (const float*)d_in[15];
    const int*   numgt = (const int*)d_in[16];

    char* ws = (char*)d_ws;
    size_t off = 0;
    State* st = (State*)(ws + off);                              off += 4096;
    unsigned* slices = (unsigned*)(ws + off);                    off += (size_t)NSLICE * 512 * 4;     // 256 KiB
    unsigned long long* cand = (unsigned long long*)(ws + off);  off += (size_t)2 * CAP * 8;          // 256 KiB
    unsigned short* part = (unsigned short*)(ws + off);          off += (size_t)2 * JSPLIT * CAP * 2; // 1 MiB
    unsigned* selIdx = (unsigned*)(ws + off);                    off += (size_t)2 * K_TOP * 4;        // 80 KiB

    float* out = (float*)d_out;

    k_hist8<<<dim3(NSLICE), dim3(512), 0, stream>>>(p.cls[0], p.cls[1], slices);
    k_pick2<<<dim3(2), dim3(512), 0, stream>>>(p.cls[0], p.cls[1], slices, st);
    k_compact<<<dim3(96, 2), dim3(256), 0, stream>>>(p.cls[0], p.cls[1], st, cand);
    k_rankpart<<<dim3(16, JSPLIT, 2), dim3(256), 0, stream>>>(st, cand, part);
    k_scatter<<<dim3(CAP / 256, 2), dim3(256), 0, stream>>>(st, cand, part, selIdx);
    k_ioudecode<<<dim3((Q4 * ISUB + 511) / 512), dim3(512), 0, stream>>>(p, selIdx, gt, numgt, out);
}

// Round 11
// 101.781 us; speedup vs baseline: 6.8682x; 1.0348x over previous
//
#include <hip/hip_runtime.h>
#include <stdint.h>

#define K_TOP 10000
#define CAP   16384            // candidate slack per level (cnt <= K + threshold-bin spill)
#define N0    98304
#define N1    24576
#define N2    6144
#define N3    1536
#define N4    384
#define NSMALL (N2 + N3 + N4)  // 8064
#define NROWS  (2 * K_TOP + NSMALL)   // 28064
#define Q4     (NROWS / 4)            // 7016 (exact)
#define MAXGT 2048
#define JSPLIT 16
#define ICHUNK 1024
#define NSLICE 128             // hist8 blocks
#define ISUB   32              // lanes per row-quad in ioudecode

struct State { unsigned prefix[2]; unsigned candCount[2]; };

struct Ptrs { const float* anc[5]; const float* cls[5]; const float* reg[5]; };

// order-preserving float->uint map (ascending uint == ascending float)
__device__ __forceinline__ unsigned f2ord(float f) {
    unsigned u = __float_as_uint(f);
    return (u & 0x80000000u) ? ~u : (u | 0x80000000u);
}

// Pass-0: top-8-bit histogram, per-wave LDS privatization, per-block slice output.
__global__ void __launch_bounds__(512)
k_hist8(const float* __restrict__ cls0, const float* __restrict__ cls1,
        unsigned* __restrict__ slices) {
    __shared__ unsigned h[8][512];       // [wave][lev*256 + bin], 16 KiB
    unsigned tid = threadIdx.x;
    for (unsigned i = tid; i < 8u * 512u; i += 512u) ((unsigned*)h)[i] = 0;
    __syncthreads();
    unsigned wave = tid >> 6;
    const unsigned NQ0 = N0 / 4, NQ1 = N1 / 4;
    for (unsigned q = blockIdx.x * 512u + tid; q < NQ0 + NQ1; q += NSLICE * 512u) {
        int lev = (q < NQ0) ? 0 : 1;
        const float4* src = lev ? (const float4*)cls1 : (const float4*)cls0;
        float4 v = src[lev ? (q - NQ0) : q];
        unsigned base = (unsigned)lev * 256u;
        atomicAdd(&h[wave][base + (f2ord(v.x) >> 24)], 1u);
        atomicAdd(&h[wave][base + (f2ord(v.y) >> 24)], 1u);
        atomicAdd(&h[wave][base + (f2ord(v.z) >> 24)], 1u);
        atomicAdd(&h[wave][base + (f2ord(v.w) >> 24)], 1u);
    }
    __syncthreads();
    unsigned s = 0;
    #pragma unroll
    for (int w2 = 0; w2 < 8; w2++) s += h[w2][tid];
    slices[blockIdx.x * 512u + tid] = s;
}

// 2 blocks (one level each): sum slices -> top byte; re-read level in-block to
// histogram the 2nd byte (wave-private LDS) -> exact 16-bit threshold.
// Also zeroes candCount.
__global__ void __launch_bounds__(512)
k_pick2(const float* __restrict__ cls0, const float* __restrict__ cls1,
        const unsigned* __restrict__ slices, State* st) {
    int lev = blockIdx.x;
    unsigned tid = threadIdx.x;
    __shared__ unsigned sfx[256];
    __shared__ unsigned h2[8][256];     // 8 KiB
    __shared__ unsigned sd[2];          // [0]=crossing bin, [1]=remK
    if (tid < 256) {
        unsigned s = 0;
        for (int k = 0; k < NSLICE; k++) s += slices[(unsigned)k * 512u + (unsigned)lev * 256u + tid];
        sfx[tid] = s;
    }
    __syncthreads();
    for (int off = 1; off < 256; off <<= 1) {     // inclusive suffix sum
        unsigned v = 0;
        if (tid < 256) v = sfx[tid] + ((tid + off < 256) ? sfx[tid + off] : 0u);
        __syncthreads();
        if (tid < 256) sfx[tid] = v;
        __syncthreads();
    }
    if (tid < 256) {
        unsigned suf = sfx[tid];
        unsigned sufN = (tid < 255) ? sfx[tid + 1] : 0u;
        if (suf >= K_TOP && sufN < K_TOP) { sd[0] = tid; sd[1] = K_TOP - sufN; }
    }
    for (unsigned i = tid; i < 8u * 256u; i += 512u) ((unsigned*)h2)[i] = 0;
    __syncthreads();
    unsigned tb = sd[0], remK = sd[1];
    unsigned wave = tid >> 6;
    const float4* src = lev ? (const float4*)cls1 : (const float4*)cls0;
    unsigned nq = (lev ? N1 : N0) / 4;
    for (unsigned q = tid; q < nq; q += 512u) {
        float4 v = src[q];
        unsigned k0 = f2ord(v.x), k1 = f2ord(v.y), k2 = f2ord(v.z), k3 = f2ord(v.w);
        if ((k0 >> 24) == tb) atomicAdd(&h2[wave][(k0 >> 16) & 255u], 1u);
        if ((k1 >> 24) == tb) atomicAdd(&h2[wave][(k1 >> 16) & 255u], 1u);
        if ((k2 >> 24) == tb) atomicAdd(&h2[wave][(k2 >> 16) & 255u], 1u);
        if ((k3 >> 24) == tb) atomicAdd(&h2[wave][(k3 >> 16) & 255u], 1u);
    }
    __syncthreads();
    if (tid < 256) {
        unsigned s = 0;
        #pragma unroll
        for (int w2 = 0; w2 < 8; w2++) s += h2[w2][tid];
        sfx[tid] = s;
    }
    __syncthreads();
    for (int off = 1; off < 256; off <<= 1) {
        unsigned v = 0;
        if (tid < 256) v = sfx[tid] + ((tid + off < 256) ? sfx[tid + off] : 0u);
        __syncthreads();
        if (tid < 256) sfx[tid] = v;
        __syncthreads();
    }
    if (tid < 256) {
        unsigned suf = sfx[tid];
        unsigned sufN = (tid < 255) ? sfx[tid + 1] : 0u;
        if (suf >= remK && sufN < remK) sd[0] = tid;
    }
    __syncthreads();
    if (tid == 0) {
        st->prefix[lev] = ((tb << 8) | sd[0]) << 16;
        st->candCount[lev] = 0;
    }
}

// Compact with block-aggregated slot allocation: ONE global RMW per block.
// Order within cand is nondeterministic but the rank pass makes order exact.
__global__ void __launch_bounds__(256)
k_compact(const float* __restrict__ cls0, const float* __restrict__ cls1,
          State* st, unsigned long long* __restrict__ cand) {
    int lev = blockIdx.y;
    const float* cls = lev ? cls1 : cls0;
    unsigned n = lev ? N1 : N0;
    unsigned T = st->prefix[lev];
    unsigned stride = gridDim.x * 256u;
    unsigned iters = (n + stride - 1u) / stride;
    unsigned long long l0 = 0, l1 = 0, l2 = 0, l3 = 0;    // static-indexed stash
    unsigned c = 0;
    unsigned i = blockIdx.x * 256u + threadIdx.x;
    for (unsigned t = 0; t < iters; t++, i += stride) {
        if (i < n) {
            unsigned key = f2ord(cls[i]);
            if (key >= T) {
                unsigned long long v = ((unsigned long long)key << 32) | (unsigned)(~i);
                if (c == 0) l0 = v; else if (c == 1) l1 = v;
                else if (c == 2) l2 = v; else l3 = v;
                c++;
            }
        }
    }
    __shared__ unsigned lcnt, gbase;
    if (threadIdx.x == 0) lcnt = 0;
    __syncthreads();
    unsigned ls = 0;
    if (c) ls = atomicAdd(&lcnt, c);
    __syncthreads();
    if (threadIdx.x == 0) gbase = atomicAdd(&st->candCount[lev], lcnt);
    __syncthreads();
    unsigned b = gbase + ls;
    unsigned long long* cl = cand + (size_t)lev * CAP;
    if (c > 0 && b + 0 < CAP) cl[b + 0] = l0;
    if (c > 1 && b + 1 < CAP) cl[b + 1] = l1;
    if (c > 2 && b + 2 < CAP) cl[b + 2] = l2;
    if (c > 3 && b + 3 < CAP) cl[b + 3] = l3;
}

// partial counting-rank: grid (16 ic, 16 jc, 2 lev); uniform bounds, 4 keys/thread
__global__ void __launch_bounds__(256)
k_rankpart(State* st, const unsigned long long* __restrict__ cand,
           unsigned short* __restrict__ part) {
    int lev = blockIdx.z;
    unsigned cnt = st->candCount[lev];
    if (cnt > CAP) cnt = CAP;
    unsigned ibase = blockIdx.x * ICHUNK;
    if (ibase >= cnt) return;                 // block-uniform
    unsigned tid = threadIdx.x;
    unsigned long long ci0, ci1, ci2, ci3;
    {
        const unsigned long long* cl = cand + (size_t)lev * CAP + ibase + tid;
        ci0 = (ibase + tid       < cnt) ? cl[0]   : 0xFFFFFFFFFFFFFFFFull;
        ci1 = (ibase + tid + 256 < cnt) ? cl[256] : 0xFFFFFFFFFFFFFFFFull;
        ci2 = (ibase + tid + 512 < cnt) ? cl[512] : 0xFFFFFFFFFFFFFFFFull;
        ci3 = (ibase + tid + 768 < cnt) ? cl[768] : 0xFFFFFFFFFFFFFFFFull;
    }
    unsigned jchunk = (cnt + JSPLIT - 1) / JSPLIT;
    unsigned j0 = blockIdx.y * jchunk;
    unsigned j1 = j0 + jchunk; if (j1 > cnt) j1 = cnt;
    unsigned rk0 = 0, rk1 = 0, rk2 = 0, rk3 = 0;
    __shared__ unsigned long long tile[256];
    for (unsigned base = j0; base < j1; base += 256) {
        unsigned j = base + tid;
        tile[tid] = (j < j1) ? cand[(size_t)lev * CAP + j] : 0ull;
        __syncthreads();
        unsigned lim = j1 - base; if (lim > 256u) lim = 256u;   // block-uniform
        #pragma unroll 4
        for (unsigned t = 0; t < lim; t++) {
            unsigned long long cj = tile[t];
            rk0 += (cj > ci0) ? 1u : 0u;
            rk1 += (cj > ci1) ? 1u : 0u;
            rk2 += (cj > ci2) ? 1u : 0u;
            rk3 += (cj > ci3) ? 1u : 0u;
        }
        __syncthreads();
    }
    unsigned short* pp = part + ((size_t)(lev * JSPLIT + blockIdx.y)) * CAP + ibase + tid;
    pp[0]   = (unsigned short)rk0;
    pp[256] = (unsigned short)rk1;
    pp[512] = (unsigned short)rk2;
    pp[768] = (unsigned short)rk3;
}

__global__ void __launch_bounds__(256)
k_scatter(State* st, const unsigned long long* __restrict__ cand,
          const unsigned short* __restrict__ part, unsigned* __restrict__ selIdx) {
    int lev = blockIdx.y;
    unsigned cnt = st->candCount[lev];
    if (cnt > CAP) cnt = CAP;
    unsigned i = blockIdx.x * 256 + threadIdx.x;
    if (i >= cnt) return;
    unsigned rank = 0;
    #pragma unroll
    for (int s = 0; s < JSPLIT; s++)
        rank += part[((size_t)(lev * JSPLIT + s)) * CAP + i];
    if (rank < K_TOP)
        selIdx[lev * K_TOP + rank] = ~(unsigned)cand[(size_t)lev * CAP + i];
}

// Fused decode + IoU argmax + targets. 32-lane group owns 4 rows (u + j*Q4);
// one GT read per iteration serves 4 pairs per lane (LDS amortization) while
// 439 blocks keep ~14 waves/CU resident (TLP).
__global__ void __launch_bounds__(512)
k_ioudecode(Ptrs p, const unsigned* __restrict__ selIdx,
            const float* __restrict__ gt, const int* __restrict__ numgt,
            float* __restrict__ out) {
    __shared__ float4 sg[MAXGT];
    __shared__ float  sarea[MAXGT];
    int ng = *numgt; if (ng > MAXGT) ng = MAXGT;
    for (int g = (int)threadIdx.x; g < ng; g += 512) {
        float x1 = gt[g * 5 + 0], y1 = gt[g * 5 + 1];
        float x2 = gt[g * 5 + 2], y2 = gt[g * 5 + 3];
        sg[g] = make_float4(x1, y1, x2, y2);
        sarea[g] = (x2 - x1 + 1.0f) * (y2 - y1 + 1.0f);
    }
    __syncthreads();

    unsigned gid = blockIdx.x * 512u + threadIdx.x;
    unsigned u = gid >> 5;
    int sub = (int)(gid & 31u);
    if (u >= (unsigned)Q4) return;    // exits in whole 32-lane groups

    // ---- decode: lanes sub<4 each decode row u + sub*Q4, keep anchor geometry ----
    float dbx1 = 0.f, dby1 = 0.f, dbx2 = 0.f, dby2 = 0.f;
    float dw = 1.f, dh = 1.f, dcx = 0.f, dcy = 0.f;
    if (sub < 4) {
        int r = (int)u + sub * Q4;
        int lev, ai;
        if (r < 2 * K_TOP) {
            lev = (r < K_TOP) ? 0 : 1;
            ai = (int)selIdx[r];
        } else {
            int rr = r - 2 * K_TOP;
            if (rr < N2)           { lev = 2; ai = rr; }
            else if (rr < N2 + N3) { lev = 3; ai = rr - N2; }
            else                   { lev = 4; ai = rr - N2 - N3; }
        }
        float4 a4 = ((const float4*)p.anc[lev])[ai];
        float sc = p.cls[lev][ai];
        float4 r4 = *(const float4*)(p.reg[lev] + (size_t)ai * 8);
        dw = a4.z - a4.x + 1.0f;  dh = a4.w - a4.y + 1.0f;
        dcx = a4.x + 0.5f * dw;   dcy = a4.y + 0.5f * dh;
        float pcx = r4.x * dw + dcx, pcy = r4.y * dh + dcy;
        float pw = expf(r4.z) * dw,  ph = expf(r4.w) * dh;
        dbx1 = pcx - 0.5f * pw;   dby1 = pcy - 0.5f * ph;
        dbx2 = pcx + 0.5f * pw - 1.0f;
        dby2 = pcy + 0.5f * ph - 1.0f;
        float* o = out + (size_t)r * 10;
        o[0] = dbx1; o[1] = dby1; o[2] = dbx2; o[3] = dby2;
        o[4] = 1.0f / (1.0f + expf(-sc));
        o[5] = 1.0f;
    }
    int base = (int)(threadIdx.x & 63u) & ~31;
    // broadcast the 4 decoded boxes to all 32 lanes of the group
    float x10 = __shfl(dbx1, base + 0, 64), y10 = __shfl(dby1, base + 0, 64);
    float x20 = __shfl(dbx2, base + 0, 64), y20 = __shfl(dby2, base + 0, 64);
    float x11 = __shfl(dbx1, base + 1, 64), y11 = __shfl(dby1, base + 1, 64);
    float x21 = __shfl(dbx2, base + 1, 64), y21 = __shfl(dby2, base + 1, 64);
    float x12 = __shfl(dbx1, base + 2, 64), y12 = __shfl(dby1, base + 2, 64);
    float x22 = __shfl(dbx2, base + 2, 64), y22 = __shfl(dby2, base + 2, 64);
    float x13 = __shfl(dbx1, base + 3, 64), y13 = __shfl(dby1, base + 3, 64);
    float x23 = __shfl(dbx2, base + 3, 64), y23 = __shfl(dby2, base + 3, 64);
    float A0 = (x20 - x10 + 1.0f) * (y20 - y10 + 1.0f);
    float A1 = (x21 - x11 + 1.0f) * (y21 - y11 + 1.0f);
    float A2 = (x22 - x12 + 1.0f) * (y22 - y12 + 1.0f);
    float A3 = (x23 - x13 + 1.0f) * (y23 - y13 + 1.0f);

    int chunk = (ng + ISUB - 1) / ISUB;
    int g0 = sub * chunk;
    int g1 = g0 + chunk; if (g1 > ng) g1 = ng; if (g0 > g1) g0 = g1;
    // iou_a > iou_b  <=>  I_a*S_b > I_b*S_a  with S = areaBox + areaGT (I terms cancel)
    float I0 = 0.f, S0 = 1.f; int a0 = (sub == 0) ? 0 : 0x7FFFFFFF;
    float I1 = 0.f, S1 = 1.f; int a1 = (sub == 0) ? 0 : 0x7FFFFFFF;
    float I2 = 0.f, S2 = 1.f; int a2 = (sub == 0) ? 0 : 0x7FFFFFFF;
    float I3 = 0.f, S3 = 1.f; int a3 = (sub == 0) ? 0 : 0x7FFFFFFF;
    for (int g = g0; g < g1; ++g) {
        float4 gb = sg[g];
        float sa = sarea[g];
        float iw, ih, I, S;
        iw = fminf(x20, gb.z) - fmaxf(x10, gb.x) + 1.0f; iw = fmaxf(iw, 0.f);
        ih = fminf(y20, gb.w) - fmaxf(y10, gb.y) + 1.0f; ih = fmaxf(ih, 0.f);
        I = iw * ih; S = A0 + sa;
        if (I * S0 > I0 * S) { I0 = I; S0 = S; a0 = g; }
        iw = fminf(x21, gb.z) - fmaxf(x11, gb.x) + 1.0f; iw = fmaxf(iw, 0.f);
        ih = fminf(y21, gb.w) - fmaxf(y11, gb.y) + 1.0f; ih = fmaxf(ih, 0.f);
        I = iw * ih; S = A1 + sa;
        if (I * S1 > I1 * S) { I1 = I; S1 = S; a1 = g; }
        iw = fminf(x22, gb.z) - fmaxf(x12, gb.x) + 1.0f; iw = fmaxf(iw, 0.f);
        ih = fminf(y22, gb.w) - fmaxf(y12, gb.y) + 1.0f; ih = fmaxf(ih, 0.f);
        I = iw * ih; S = A2 + sa;
        if (I * S2 > I2 * S) { I2 = I; S2 = S; a2 = g; }
        iw = fminf(x23, gb.z) - fmaxf(x13, gb.x) + 1.0f; iw = fmaxf(iw, 0.f);
        ih = fminf(y23, gb.w) - fmaxf(y13, gb.y) + 1.0f; ih = fmaxf(ih, 0.f);
        I = iw * ih; S = A3 + sa;
        if (I * S3 > I3 * S) { I3 = I; S3 = S; a3 = g; }
    }
    // reduce across 32 lanes: max iou, tie -> min index (== sequential first-max)
    #pragma unroll
    for (int off = 1; off < 32; off <<= 1) {
        float oI, oS, x, y; int oa;
        oI = __shfl_xor(I0, off); oS = __shfl_xor(S0, off); oa = __shfl_xor(a0, off);
        x = oI * S0; y = I0 * oS;
        if (x > y || (x == y && oa < a0)) { I0 = oI; S0 = oS; a0 = oa; }
        oI = __shfl_xor(I1, off); oS = __shfl_xor(S1, off); oa = __shfl_xor(a1, off);
        x = oI * S1; y = I1 * oS;
        if (x > y || (x == y && oa < a1)) { I1 = oI; S1 = oS; a1 = oa; }
        oI = __shfl_xor(I2, off); oS = __shfl_xor(S2, off); oa = __shfl_xor(a2, off);
        x = oI * S2; y = I2 * oS;
        if (x > y || (x == y && oa < a2)) { I2 = oI; S2 = oS; a2 = oa; }
        oI = __shfl_xor(I3, off); oS = __shfl_xor(S3, off); oa = __shfl_xor(a3, off);
        x = oI * S3; y = I3 * oS;
        if (x > y || (x == y && oa < a3)) { I3 = oI; S3 = oS; a3 = oa; }
    }
    if (sub < 4) {
        int arg = (sub == 0) ? a0 : (sub == 1) ? a1 : (sub == 2) ? a2 : a3;
        if (arg >= ng) arg = 0;
        float4 gb = sg[arg];
        float gw = gb.z - gb.x + 1.0f, gh = gb.w - gb.y + 1.0f;
        float gcx = gb.x + 0.5f * gw,  gcy = gb.y + 0.5f * gh;
        int r = (int)u + sub * Q4;
        float* o = out + (size_t)r * 10;
        o[6] = (gcx - dcx) / dw;
        o[7] = (gcy - dcy) / dh;
        o[8] = logf(gw / dw);
        o[9] = logf(gh / dh);
    }
}

extern "C" void kernel_launch(void* const* d_in, const int* in_sizes, int n_in,
                              void* d_out, int out_size, void* d_ws, size_t ws_size,
                              hipStream_t stream) {
    Ptrs p;
    bool interleaved = (in_sizes[2] == N0 * 8);
    for (int l = 0; l < 5; l++) {
        if (interleaved) {
            p.anc[l] = (const float*)d_in[3 * l + 0];
            p.cls[l] = (const float*)d_in[3 * l + 1];
            p.reg[l] = (const float*)d_in[3 * l + 2];
        } else {
            p.anc[l] = (const float*)d_in[l];
            p.cls[l] = (const float*)d_in[5 + l];
            p.reg[l] = (const float*)d_in[10 + l];
        }
    }
    const float* gt    = (const float*)d_in[15];
    const int*   numgt = (const int*)d_in[16];

    char* ws = (char*)d_ws;
    size_t off = 0;
    State* st = (State*)(ws + off);                              off += 4096;
    unsigned* slices = (unsigned*)(ws + off);                    off += (size_t)NSLICE * 512 * 4;     // 256 KiB
    unsigned long long* cand = (unsigned long long*)(ws + off);  off += (size_t)2 * CAP * 8;          // 256 KiB
    unsigned short* part = (unsigned short*)(ws + off);          off += (size_t)2 * JSPLIT * CAP * 2; // 1 MiB
    unsigned* selIdx = (unsigned*)(ws + off);                    off += (size_t)2 * K_TOP * 4;        // 80 KiB

    float* out = (float*)d_out;

    k_hist8<<<dim3(NSLICE), dim3(512), 0, stream>>>(p.cls[0], p.cls[1], slices);
    k_pick2<<<dim3(2), dim3(512), 0, stream>>>(p.cls[0], p.cls[1], slices, st);
    k_compact<<<dim3(96, 2), dim3(256), 0, stream>>>(p.cls[0], p.cls[1], st, cand);
    k_rankpart<<<dim3(16, JSPLIT, 2), dim3(256), 0, stream>>>(st, cand, part);
    k_scatter<<<dim3(CAP / 256, 2), dim3(256), 0, stream>>>(st, cand, part, selIdx);
    k_ioudecode<<<dim3((Q4 * ISUB + 511) / 512), dim3(512), 0, stream>>>(p, selIdx, gt, numgt, out);
}